// Round 17
// baseline (1876.420 us; speedup 1.0000x reference)
//
#include <hip/hip_runtime.h>
#include <hip/hip_bf16.h>
#include <stdint.h>

#define B 4096
#define DX 100
#define H 512
#define DD 100
#define NSTEPS 64
#define KIN 128      // padded K for layer 1 (101 -> 128)
#define N4 128       // padded N for layer 4 (100 -> 128)
#define NBLK 256
#define NTHR 512

typedef short bf8 __attribute__((ext_vector_type(8)));    // 8 x bf16
typedef float f32x4 __attribute__((ext_vector_type(4)));  // MFMA C/D

__device__ __forceinline__ ushort f2bf(float f) {
  union { __hip_bfloat16 h; ushort u; } cv;
  cv.h = __float2bfloat16(f);          // hw v_cvt (RNE)
  return cv.u;
}
__device__ __forceinline__ float bf2f(ushort h) {
  return __uint_as_float((uint32_t)h << 16);
}
__device__ __forceinline__ f32x4 mfma16(bf8 a, bf8 b, f32x4 c) {
  return __builtin_amdgcn_mfma_f32_16x16x32_bf16(a, b, c, 0, 0, 0);
}

// ---- swizzled LDS addressing: stride must be a multiple of 128 B so the row
// base contributes 0 (mod 8) 16B-slots; then byte ^= (row&7)<<4 spreads the
// column slot across 8 banks-windows -> conflict-free MFMA fragment reads (T2/G4).
__device__ __forceinline__ char* swz(void* base, int row, int colU, int strideU) {
  uint32_t off = ((uint32_t)(row * strideU + colU) * 2u) ^ ((uint32_t)(row & 7) << 4);
  return (char*)base + off;
}

__device__ __forceinline__ int aload_i(int* p) {
  return __hip_atomic_load(p, __ATOMIC_RELAXED, __HIP_MEMORY_SCOPE_AGENT);
}
__device__ __forceinline__ float aload_f(const float* p) {
  return __hip_atomic_load((float*)p, __ATOMIC_RELAXED, __HIP_MEMORY_SCOPE_AGENT);
}

// ---------------- JAX threefry2x32 (20 rounds) ----------------
__device__ __forceinline__ void tf2x32(uint32_t k0, uint32_t k1,
                                       uint32_t x0, uint32_t x1,
                                       uint32_t& o0, uint32_t& o1)
{
  uint32_t ks2 = 0x1BD11BDAu ^ k0 ^ k1;
  x0 += k0; x1 += k1;
#define RND(r) { x0 += x1; x1 = (x1 << (r)) | (x1 >> (32 - (r))); x1 ^= x0; }
  RND(13) RND(15) RND(26) RND(6)   x0 += k1;  x1 += ks2 + 1u;
  RND(17) RND(29) RND(16) RND(24)  x0 += ks2; x1 += k0  + 2u;
  RND(13) RND(15) RND(26) RND(6)   x0 += k0;  x1 += k1  + 3u;
  RND(17) RND(29) RND(16) RND(24)  x0 += k1;  x1 += ks2 + 4u;
  RND(13) RND(15) RND(26) RND(6)   x0 += ks2; x1 += k0  + 5u;
#undef RND
  o0 = x0; o1 = x1;
}
// threefry_partitionable=True: split(key(42),64) -> key[s] = threefry((0,42),(0,s))
__device__ __forceinline__ void step_keys(int step, uint32_t& k0, uint32_t& k1)
{
  tf2x32(0u, 42u, 0u, (uint32_t)step, k0, k1);
}
// partitionable random_bits: counter (0,m), bits = o0 ^ o1
__device__ __forceinline__ uint32_t jax_bits(uint32_t k0, uint32_t k1, uint32_t m)
{
  uint32_t a, b;
  tf2x32(k0, k1, 0u, m, a, b);
  return a ^ b;
}

__device__ __forceinline__ float jax_normal_from_bits(uint32_t bits)
{
  float f = __uint_as_float((bits >> 9) | 0x3f800000u) - 1.0f;
  const float lo = -0.99999994f;
  float u = fmaxf(lo, f * 2.0f + lo);
  float w = -log1pf(-u * u);
  float p;
  if (w < 5.0f) {
    w -= 2.5f;
    p =          2.81022636e-08f;
    p = fmaf(p, w, 3.43273939e-07f);
    p = fmaf(p, w, -3.5233877e-06f);
    p = fmaf(p, w, -4.39150654e-06f);
    p = fmaf(p, w, 0.00021858087f);
    p = fmaf(p, w, -0.00125372503f);
    p = fmaf(p, w, -0.00417768164f);
    p = fmaf(p, w, 0.246640727f);
    p = fmaf(p, w, 1.50140941f);
  } else {
    w = sqrtf(w) - 3.0f;
    p =          -0.000200214257f;
    p = fmaf(p, w, 0.000100950558f);
    p = fmaf(p, w, 0.00134934322f);
    p = fmaf(p, w, -0.00367342844f);
    p = fmaf(p, w, 0.00573950773f);
    p = fmaf(p, w, -0.0076224613f);
    p = fmaf(p, w, 0.00943887047f);
    p = fmaf(p, w, 1.00167406f);
    p = fmaf(p, w, 2.83297682f);
  }
  return 1.4142135623730951f * (p * u);
}

// fast tanh-form GELU: max |err| vs exact erf-GELU ~1e-3 (<< bf16 activation noise)
__device__ __forceinline__ float gelu(float v)
{
  float v2 = v * v;
  float zin = fmaf(0.044715f * v2, v, v);               // v + 0.044715 v^3
  float z = fminf(1.5957691216057308f * zin, 80.0f);    // 2*sqrt(2/pi)*zin, clamped
  float e = __expf(z);                                   // hw exp
  float t = (e - 1.0f) * __builtin_amdgcn_rcpf(e + 1.0f);// tanh
  float hv = 0.5f * v;
  return fmaf(hv, t, hv);
}

// ---------------- prep: bf16 transposed weights (shared by both paths) ----------------
__global__ void k_prep(const float* __restrict__ W1, const float* __restrict__ W2,
                       const float* __restrict__ W3, const float* __restrict__ W4,
                       ushort* __restrict__ w1t, ushort* __restrict__ w2t,
                       ushort* __restrict__ w3t, ushort* __restrict__ w4t)
{
  int gid = blockIdx.x * blockDim.x + threadIdx.x;
  int stride = gridDim.x * blockDim.x;
  for (int i = gid; i < H * KIN; i += stride) {
    int c = i >> 7, k = i & (KIN - 1);
    w1t[i] = f2bf(k < 101 ? W1[k * H + c] : 0.0f);
  }
  for (int i = gid; i < H * H; i += stride) {
    int c = i >> 9, k = i & (H - 1);
    w2t[i] = f2bf(W2[k * H + c]);
    w3t[i] = f2bf(W3[k * H + c]);
  }
  for (int i = gid; i < N4 * H; i += stride) {
    int c = i >> 9, k = i & (H - 1);
    w4t[i] = f2bf(c < DD ? W4[k * DD + c] : 0.0f);
  }
}

// ================================================================
// ===================  CHUNKED STEP-PARALLEL PATH  ===============
// ================================================================

__global__ void k_init_chunk(const float* __restrict__ y0, const float* __restrict__ x0,
                             float* __restrict__ x_run, float* __restrict__ y,
                             float* __restrict__ bn)
{
  int gid = blockIdx.x * blockDim.x + threadIdx.x;
  int stride = gridDim.x * blockDim.x;
  for (int i = gid; i < B * DX; i += stride) x_run[i] = x0[i % DX];
  for (int i = gid; i < B; i += stride) y[i] = y0[0];
  for (int i = gid; i < NSTEPS * 4 * H; i += stride) bn[i] = 0.0f;
}

// RNG prefix: xs[t][row][0..127] bf16 for chunk steps; carries x_run; writes final x
__global__ void k_xs(float* __restrict__ x_run, ushort* __restrict__ xs,
                     float* __restrict__ xout, int s0, int Sc)
{
  int gid = blockIdx.x * blockDim.x + threadIdx.x;   // 4096*128 threads
  int row = gid >> 7, col = gid & 127;
  const float dt = 1.0f / NSTEPS;
  if (col < DX) {
    float xr = x_run[row * DX + col];
    uint32_t m = (uint32_t)(row * DD + col);
    for (int t = 0; t < Sc; ++t) {
      xs[t * (B * KIN) + row * KIN + col] = f2bf(xr);   // x_s BEFORE this step's dW
      uint32_t k0, k1;
      step_keys(s0 + t, k0, k1);
      float dW = 0.125f * jax_normal_from_bits(jax_bits(k0, k1, m));
      xr += 1.4142135623730951f * dW;
    }
    x_run[row * DX + col] = xr;
    if (s0 + Sc == NSTEPS) xout[row * DX + col] = xr;
  } else {
    for (int t = 0; t < Sc; ++t)
      xs[t * (B * KIN) + row * KIN + col] =
          (col == DX) ? f2bf((float)(s0 + t) * dt) : (ushort)0;
  }
}

// kL12: h1 = gelu(xs@W1+b1) once per 64-row block (xs staged in swizzled LDS);
// g = gelu(h1@W2+b2) via transpose-dump; BN1 stats. grid Sc*64, 512 threads.
__global__ __launch_bounds__(512, 3) void kL12(
    const ushort* __restrict__ xs, const ushort* __restrict__ w1t,
    const float* __restrict__ b1, const ushort* __restrict__ w2t,
    const float* __restrict__ b2, ushort* __restrict__ g,
    float* __restrict__ bn, int s0)
{
  __shared__ ushort xt[64 * 128];   // swizzled, stride 128 ushorts (256 B)
  __shared__ ushort at[64 * 256];   // swizzled, stride 256 ushorts (512 B)
  const int tid = threadIdx.x;
  const int mb = blockIdx.x;
  const int base = mb * 64;
  float* bns = bn + (s0 + (mb >> 6)) * 4 * H;
  float* bnq = bns + H;
  const int w = tid >> 6, lane = tid & 63, lr = lane & 15, lg = lane >> 4;

  for (int i = tid; i < 64 * 16; i += 512) {   // 64 rows x 16 bf8
    int r = i >> 4, kk = (i & 15) * 8;
    *(bf8*)swz(xt, r, kk, 128) = *(const bf8*)&xs[(size_t)(base + r) * KIN + kk];
  }
  __syncthreads();

  f32x4 acc[4][4];
#pragma unroll
  for (int mi = 0; mi < 4; mi++)
#pragma unroll
    for (int t = 0; t < 4; t++) acc[mi][t] = (f32x4)(0.0f);

#pragma unroll
  for (int c = 0; c < 2; c++) {
    if (c) __syncthreads();   // at consumed by GEMM2 of c=0
    // ---- GEMM1: wave computes h1 cols [c*256 + w*32, +32); B hoisted per u
#pragma unroll
    for (int u = 0; u < 2; u++) {
      int hcol = c * 256 + w * 32 + u * 16 + lr;
      bf8 bfr[4];
#pragma unroll
      for (int ks = 0; ks < 4; ks++)
        bfr[ks] = *(const bf8*)(w1t + hcol * KIN + ks * 32 + lg * 8);
      f32x4 a1[4];
#pragma unroll
      for (int mi = 0; mi < 4; mi++) a1[mi] = (f32x4)(0.0f);
#pragma unroll
      for (int ks = 0; ks < 4; ks++) {
#pragma unroll
        for (int mi = 0; mi < 4; mi++) {
          bf8 a = *(const bf8*)swz(xt, mi * 16 + lr, ks * 32 + lg * 8, 128);
          a1[mi] = mfma16(a, bfr[ks], a1[mi]);
        }
      }
      int lcol = w * 32 + u * 16 + lr;
      float bb = b1[c * 256 + lcol];
#pragma unroll
      for (int mi = 0; mi < 4; mi++)
#pragma unroll
        for (int r = 0; r < 4; r++)
          *(ushort*)swz(at, mi * 16 + lg * 4 + r, lcol, 256) = f2bf(gelu(a1[mi][r] + bb));
    }
    __syncthreads();   // at (h1 chunk) ready
    // ---- GEMM2 partial: K slice [c*256, +256); 2-deep B prefetch over ks
    {
      bf8 bnx[4];
#pragma unroll
      for (int t = 0; t < 4; t++) {
        int col = w * 64 + t * 16 + lr;
        bnx[t] = *(const bf8*)(w2t + col * H + c * 256 + 0 * 32 + lg * 8);
      }
#pragma unroll
      for (int ks = 0; ks < 8; ks++) {
        bf8 bcur[4];
#pragma unroll
        for (int t = 0; t < 4; t++) bcur[t] = bnx[t];
        if (ks < 7) {
#pragma unroll
          for (int t = 0; t < 4; t++) {
            int col = w * 64 + t * 16 + lr;
            bnx[t] = *(const bf8*)(w2t + col * H + c * 256 + (ks + 1) * 32 + lg * 8);
          }
        }
        bf8 af[4];
#pragma unroll
        for (int mi = 0; mi < 4; mi++)
          af[mi] = *(const bf8*)swz(at, mi * 16 + lr, ks * 32 + lg * 8, 256);
#pragma unroll
        for (int t = 0; t < 4; t++)
#pragma unroll
          for (int mi = 0; mi < 4; mi++)
            acc[mi][t] = mfma16(af[mi], bcur[t], acc[mi][t]);
      }
    }
  }

  // ---- epilogue: gelu -> at (transpose) -> vectorized dump; BN1 stats
#pragma unroll
  for (int p = 0; p < 2; p++) {
    __syncthreads();   // at free (GEMM2 done / previous dump read done)
#pragma unroll
    for (int tt = 0; tt < 2; tt++) {
      int t = 2 * p + tt;
      int col = w * 64 + t * 16 + lr;
      float bb = b2[col], s = 0.0f, q = 0.0f;
#pragma unroll
      for (int mi = 0; mi < 4; mi++)
#pragma unroll
        for (int r = 0; r < 4; r++) {
          float v = gelu(acc[mi][t][r] + bb);
          *(ushort*)swz(at, mi * 16 + lg * 4 + r, w * 32 + tt * 16 + lr, 256) = f2bf(v);
          s += v; q += v * v;
        }
      s += __shfl_xor(s, 16); s += __shfl_xor(s, 32);
      q += __shfl_xor(q, 16); q += __shfl_xor(q, 32);
      if (lane < 16) { unsafeAtomicAdd(&bns[col], s); unsafeAtomicAdd(&bnq[col], q); }
    }
    __syncthreads();
#pragma unroll
    for (int k = 0; k < 4; k++) {
      int slot = tid + k * 512;          // 2048 bf8 slots = 64 rows x 32 col-groups
      int row = slot >> 5, jc = slot & 31;
      int gcol = (jc >> 2) * 64 + 32 * p + (jc & 3) * 8;
      *(bf8*)&g[(size_t)(base + row) * H + gcol] = *(const bf8*)swz(at, row, jc * 8, 256);
    }
  }
}

// kL3: n2 = BN1(g); g = gelu(n2@W3+b3) IN PLACE; BN2 stats. grid Sc*64, 512 thr.
__global__ __launch_bounds__(512, 4) void kL3(
    ushort* __restrict__ g, float* __restrict__ bn, int s0,
    const float* __restrict__ gamma, const float* __restrict__ beta,
    const ushort* __restrict__ w3t, const float* __restrict__ b3)
{
  __shared__ float sc[H], sh[H];
  __shared__ ushort at[64 * 256];   // swizzled
  const int tid = threadIdx.x;
  const int mb = blockIdx.x;
  const int base = mb * 64;
  float* bn1s = bn + (s0 + (mb >> 6)) * 4 * H;
  float* bn1q = bn1s + H;
  float* bn2s = bn1s + 2 * H;
  float* bn2q = bn1s + 3 * H;
  const int w = tid >> 6, lane = tid & 63, lr = lane & 15, lg = lane >> 4;

  for (int c = tid; c < H; c += 512) {
    float m = bn1s[c] * (1.0f / B);
    float v = bn1q[c] * (1.0f / B) - m * m;
    float s2_ = gamma[c] * rsqrtf(v + 1e-5f);
    sc[c] = s2_; sh[c] = beta[c] - m * s2_;
  }

  f32x4 acc[4][4];
#pragma unroll
  for (int mi = 0; mi < 4; mi++)
#pragma unroll
    for (int t = 0; t < 4; t++) acc[mi][t] = (f32x4)(0.0f);

#pragma unroll
  for (int c = 0; c < 2; c++) {
    __syncthreads();   // c=0: sc/sh ready; c=1: at consumed
    for (int i = tid; i < 4096; i += 512) {         // 64 rows x 64 vec4
      int r = i >> 6, k4 = (i & 63) * 4, gk = c * 256 + k4;
      ushort4 gv = *(const ushort4*)&g[(size_t)(base + r) * H + gk];
      ushort4 o;
      o.x = f2bf(fmaf(bf2f(gv.x), sc[gk + 0], sh[gk + 0]));
      o.y = f2bf(fmaf(bf2f(gv.y), sc[gk + 1], sh[gk + 1]));
      o.z = f2bf(fmaf(bf2f(gv.z), sc[gk + 2], sh[gk + 2]));
      o.w = f2bf(fmaf(bf2f(gv.w), sc[gk + 3], sh[gk + 3]));
      *(ushort4*)swz(at, r, k4, 256) = o;
    }
    __syncthreads();
    {
      bf8 bnx[4];
#pragma unroll
      for (int t = 0; t < 4; t++) {
        int col = w * 64 + t * 16 + lr;
        bnx[t] = *(const bf8*)(w3t + col * H + c * 256 + 0 * 32 + lg * 8);
      }
#pragma unroll
      for (int ks = 0; ks < 8; ks++) {
        bf8 bcur[4];
#pragma unroll
        for (int t = 0; t < 4; t++) bcur[t] = bnx[t];
        if (ks < 7) {
#pragma unroll
          for (int t = 0; t < 4; t++) {
            int col = w * 64 + t * 16 + lr;
            bnx[t] = *(const bf8*)(w3t + col * H + c * 256 + (ks + 1) * 32 + lg * 8);
          }
        }
        bf8 af[4];
#pragma unroll
        for (int mi = 0; mi < 4; mi++)
          af[mi] = *(const bf8*)swz(at, mi * 16 + lr, ks * 32 + lg * 8, 256);
#pragma unroll
        for (int t = 0; t < 4; t++)
#pragma unroll
          for (int mi = 0; mi < 4; mi++)
            acc[mi][t] = mfma16(af[mi], bcur[t], acc[mi][t]);
      }
    }
  }

  // ---- epilogue: gelu -> at -> vectorized in-place dump; BN2 stats
#pragma unroll
  for (int p = 0; p < 2; p++) {
    __syncthreads();
#pragma unroll
    for (int tt = 0; tt < 2; tt++) {
      int t = 2 * p + tt;
      int col = w * 64 + t * 16 + lr;
      float bb = b3[col], s = 0.0f, q = 0.0f;
#pragma unroll
      for (int mi = 0; mi < 4; mi++)
#pragma unroll
        for (int r = 0; r < 4; r++) {
          float v = gelu(acc[mi][t][r] + bb);
          *(ushort*)swz(at, mi * 16 + lg * 4 + r, w * 32 + tt * 16 + lr, 256) = f2bf(v);
          s += v; q += v * v;
        }
      s += __shfl_xor(s, 16); s += __shfl_xor(s, 32);
      q += __shfl_xor(q, 16); q += __shfl_xor(q, 32);
      if (lane < 16) { unsafeAtomicAdd(&bn2s[col], s); unsafeAtomicAdd(&bn2q[col], q); }
    }
    __syncthreads();
#pragma unroll
    for (int k = 0; k < 4; k++) {
      int slot = tid + k * 512;
      int row = slot >> 5, jc = slot & 31;
      int gcol = (jc >> 2) * 64 + 32 * p + (jc & 3) * 8;
      *(bf8*)&g[(size_t)(base + row) * H + gcol] = *(const bf8*)swz(at, row, jc * 8, 256);
    }
  }
}

// kL4: n3 = BN2(g); z = n3@W4+b4; RNG recompute; y atomics.
// grid Sc*128, 512 thr: 32 rows per block. All 16 B-fragments hoisted.
__global__ __launch_bounds__(512, 3) void kL4(
    const ushort* __restrict__ g, const float* __restrict__ bn, int s0,
    const float* __restrict__ gamma, const float* __restrict__ beta,
    const ushort* __restrict__ w4t, const float* __restrict__ b4,
    float* __restrict__ y)
{
  __shared__ float sc[H], sh[H];
  __shared__ ushort at[32 * 512];   // swizzled, stride 512 ushorts (1024 B)
  __shared__ float ys1[8][32], ys2[8][32];
  const int tid = threadIdx.x;
  const int sb = blockIdx.x >> 7;           // step within chunk
  const int s = s0 + sb;
  const int lb = (blockIdx.x & 127) * 32;   // row base within step's batch
  const int rbase = sb * B + lb;            // row base in chunk buffer
  const float dt = 1.0f / NSTEPS;
  const float* bn2s = bn + s * 4 * H + 2 * H;
  const float* bn2q = bn2s + H;

  const int w = tid >> 6, lane = tid & 63, lr = lane & 15, lg = lane >> 4;
  const int col = w * 16 + lr;              // 0..127 (w4t zero-padded)

  // hoist all 16 B fragments (independent of LDS phase)
  bf8 ball[16];
#pragma unroll
  for (int ks = 0; ks < 16; ks++)
    ball[ks] = *(const bf8*)(w4t + col * H + ks * 32 + lg * 8);

  for (int c = tid; c < H; c += 512) {
    float m = bn2s[c] * (1.0f / B);
    float v = bn2q[c] * (1.0f / B) - m * m;
    float s2_ = gamma[c] * rsqrtf(v + 1e-5f);
    sc[c] = s2_; sh[c] = beta[c] - m * s2_;
  }
  __syncthreads();
  for (int i = tid; i < 32 * 128; i += 512) {   // 32 rows x 128 vec4
    int r = i >> 7, k4 = (i & 127) * 4;
    ushort4 gv = *(const ushort4*)&g[(size_t)(rbase + r) * H + k4];
    ushort4 o;
    o.x = f2bf(fmaf(bf2f(gv.x), sc[k4 + 0], sh[k4 + 0]));
    o.y = f2bf(fmaf(bf2f(gv.y), sc[k4 + 1], sh[k4 + 1]));
    o.z = f2bf(fmaf(bf2f(gv.z), sc[k4 + 2], sh[k4 + 2]));
    o.w = f2bf(fmaf(bf2f(gv.w), sc[k4 + 3], sh[k4 + 3]));
    *(ushort4*)swz(at, r, k4, 512) = o;
  }
  __syncthreads();

  f32x4 acc[2];
  acc[0] = (f32x4)(0.0f); acc[1] = (f32x4)(0.0f);
#pragma unroll
  for (int ks = 0; ks < 16; ks++) {
#pragma unroll
    for (int mi = 0; mi < 2; mi++) {
      bf8 a = *(const bf8*)swz(at, mi * 16 + lr, ks * 32 + lg * 8, 512);
      acc[mi] = mfma16(a, ball[ks], acc[mi]);
    }
  }

  uint32_t k0, k1;
  step_keys(s, k0, k1);
#pragma unroll
  for (int mi = 0; mi < 2; mi++) {
    float zz[4] = {0, 0, 0, 0}, zw[4] = {0, 0, 0, 0};
    if (col < DD) {
      float bb = b4[col];
#pragma unroll
      for (int r = 0; r < 4; r++) {
        int lrow = lb + mi * 16 + lg * 4 + r;   // row within this step's batch
        float z = acc[mi][r] + bb;
        uint32_t m = (uint32_t)lrow * (uint32_t)DD + (uint32_t)col;
        float dW = 0.125f * jax_normal_from_bits(jax_bits(k0, k1, m));
        zz[r] = z * z;
        zw[r] = z * dW;
      }
    }
#pragma unroll
    for (int r = 0; r < 4; r++) {
      zz[r] += __shfl_xor(zz[r], 1); zz[r] += __shfl_xor(zz[r], 2);
      zz[r] += __shfl_xor(zz[r], 4); zz[r] += __shfl_xor(zz[r], 8);
      zw[r] += __shfl_xor(zw[r], 1); zw[r] += __shfl_xor(zw[r], 2);
      zw[r] += __shfl_xor(zw[r], 4); zw[r] += __shfl_xor(zw[r], 8);
    }
    if (lr == 0) {
#pragma unroll
      for (int r = 0; r < 4; r++) {
        ys1[w][mi * 16 + lg * 4 + r] = zz[r];
        ys2[w][mi * 16 + lg * 4 + r] = zw[r];
      }
    }
  }
  __syncthreads();
  if (tid < 32) {
    float s1 = 0.0f, s2_ = 0.0f;
#pragma unroll
    for (int i = 0; i < 8; i++) { s1 += ys1[i][tid]; s2_ += ys2[i][tid]; }
    unsafeAtomicAdd(&y[lb + tid], 0.5f * dt * s1 + s2_);
  }
}

// ================================================================
// =============  ROUND-9 COOPERATIVE FALLBACK PATH  ==============
// ================================================================

__device__ __forceinline__ void gbar(int* cnt, int* gen, int mode)
{
  if (mode) __builtin_amdgcn_fence(__ATOMIC_RELEASE, "agent");
  __syncthreads();
  if (threadIdx.x == 0) {
    int g = aload_i(gen);
    int a = __hip_atomic_fetch_add(cnt, 1, __ATOMIC_RELAXED, __HIP_MEMORY_SCOPE_AGENT);
    if (a == NBLK - 1) {
      __hip_atomic_store(cnt, 0, __ATOMIC_RELAXED, __HIP_MEMORY_SCOPE_AGENT);
      __hip_atomic_store(gen, g + 1, __ATOMIC_RELAXED, __HIP_MEMORY_SCOPE_AGENT);
    } else {
      while (aload_i(gen) == g) __builtin_amdgcn_s_sleep(2);
    }
  }
  __syncthreads();
  if (mode) __builtin_amdgcn_fence(__ATOMIC_ACQUIRE, "agent");
  else      asm volatile("buffer_inv" ::: "memory");
}

__global__ void k_init_coop(const float* __restrict__ y0, const float* __restrict__ x0,
                            float* __restrict__ x, float* __restrict__ y,
                            float* __restrict__ bn, int* __restrict__ bar)
{
  int gid = blockIdx.x * blockDim.x + threadIdx.x;
  int stride = gridDim.x * blockDim.x;
  for (int i = gid; i < B * DX; i += stride) x[i] = x0[i % DX];
  for (int i = gid; i < B; i += stride) y[i] = y0[0];
  for (int i = gid; i < NSTEPS * 4 * H; i += stride) bn[i] = 0.0f;
  if (gid < 32) bar[gid] = 0;
}

__device__ __forceinline__ void l1_sec(const ushort* xt, const ushort* __restrict__ w1t,
                                       const float* __restrict__ b1,
                                       ushort* __restrict__ h1g,
                                       int base, int w, int lr, int lg)
{
  f32x4 a1[4];
#pragma unroll
  for (int t = 0; t < 4; t++) a1[t] = (f32x4)(0.0f);
#pragma unroll
  for (int ks = 0; ks < 4; ks++) {
    bf8 a = *(const bf8*)&xt[lr * 136 + ks * 32 + lg * 8];
#pragma unroll
    for (int t = 0; t < 4; t++) {
      int cc = w * 64 + t * 16 + lr;
      bf8 bfr = *(const bf8*)(w1t + cc * KIN + ks * 32 + lg * 8);
      a1[t] = mfma16(a, bfr, a1[t]);
    }
  }
#pragma unroll
  for (int t = 0; t < 4; t++) {
    int cc = w * 64 + t * 16 + lr;
    float bb = b1[cc];
#pragma unroll
    for (int r = 0; r < 4; r++)
      h1g[(base + lg * 4 + r) * H + cc] = f2bf(gelu(a1[t][r] + bb));
  }
}

__global__ void __launch_bounds__(NTHR, 2) k_steps(
    const ushort* __restrict__ w1t, const float* __restrict__ b1,
    const ushort* __restrict__ w2t, const float* __restrict__ b2,
    const ushort* __restrict__ w3t, const float* __restrict__ b3,
    const ushort* __restrict__ w4t, const float* __restrict__ b4,
    const float* __restrict__ ga1, const float* __restrict__ be1,
    const float* __restrict__ ga2, const float* __restrict__ be2,
    ushort* __restrict__ g1, ushort* __restrict__ g2h,
    float* __restrict__ bn, float* __restrict__ x, float* __restrict__ y,
    int* __restrict__ bar)
{
  __shared__ ushort smem[64 * 264];
  __shared__ float sc[H], sh[H];
  __shared__ float ys1[8][16], ys2[8][16];
  __shared__ int dsh[2];

  const int tid = threadIdx.x;
  const int w = tid >> 6, lane = tid & 63, lr = lane & 15, lg = lane >> 4;
  const float dt = 1.0f / NSTEPS;
  int* cnt = bar; int* gen = bar + 1;
  int* bins = bar + 2;
  int* gcnt = bar + 18;

  int sgs, mode;
  {
    if (tid == 0) {
      uint32_t xcc = __builtin_amdgcn_s_getreg(20 | (31 << 11)) & 15u;
      int j = __hip_atomic_fetch_add(&bins[xcc], 1, __ATOMIC_RELAXED, __HIP_MEMORY_SCOPE_AGENT);
      dsh[0] = (int)xcc; dsh[1] = j;
    }
    gbar(cnt, gen, 1);
    if (tid == 0) {
      int ok = 1;
      for (int k = 0; k < 8; k++)  ok &= (aload_i(&bins[k]) == 32);
      for (int k = 8; k < 16; k++) ok &= (aload_i(&bins[k]) == 0);
      if (ok) { dsh[0] = dsh[0] * 32 + dsh[1]; dsh[1] = 0; }
      else {
        dsh[0] = __hip_atomic_fetch_add(gcnt, 1, __ATOMIC_RELAXED, __HIP_MEMORY_SCOPE_AGENT);
        dsh[1] = 1;
      }
    }
    __syncthreads();
    sgs = dsh[0]; mode = dsh[1];
  }
  const int mb = sgs >> 2, q = sgs & 3;
  const int cbase = sgs * 16;

  {
    ushort* xt = smem;
    for (int i = tid; i < 16 * KIN; i += NTHR) {
      int r = i >> 7, k = i & (KIN - 1);
      xt[r * 136 + k] = (k < DX) ? f2bf(x[(cbase + r) * DX + k]) : (ushort)0;
    }
    __syncthreads();
    l1_sec(xt, w1t, b1, g2h, cbase, w, lr, lg);
  }
  gbar(cnt, gen, mode);

  for (int s = 0; s < NSTEPS; ++s) {
    float* bn1s = bn + s * 4 * H;
    float* bn1q = bn1s + H;
    float* bn2s = bn1s + 2 * H;
    float* bn2q = bn1s + 3 * H;

    {
      const int col = q * 128 + w * 16 + lr;
      f32x4 acc[4];
#pragma unroll
      for (int mi = 0; mi < 4; mi++) acc[mi] = (f32x4)(0.0f);
#pragma unroll
      for (int c = 0; c < 2; c++) {
        if (c) __syncthreads();
        for (int i = tid; i < 2048; i += NTHR) {
          int r = i >> 5, kk = (i & 31) * 8;
          *(bf8*)&smem[r * 264 + kk] = *(const bf8*)&g2h[(mb * 64 + r) * H + c * 256 + kk];
        }
        __syncthreads();
#pragma unroll
        for (int ks = 0; ks < 8; ks++) {
          bf8 b = *(const bf8*)(w2t + col * H + c * 256 + ks * 32 + lg * 8);
#pragma unroll
          for (int mi = 0; mi < 4; mi++) {
            bf8 a = *(const bf8*)&smem[(mi * 16 + lr) * 264 + ks * 32 + lg * 8];
            acc[mi] = mfma16(a, b, acc[mi]);
          }
        }
      }
      float bb = b2[col], ssum = 0.0f, qsum = 0.0f;
#pragma unroll
      for (int mi = 0; mi < 4; mi++)
#pragma unroll
        for (int r = 0; r < 4; r++) {
          float v = gelu(acc[mi][r] + bb);
          g1[(mb * 64 + mi * 16 + lg * 4 + r) * H + col] = f2bf(v);
          ssum += v; qsum += v * v;
        }
      ssum += __shfl_xor(ssum, 16); ssum += __shfl_xor(ssum, 32);
      qsum += __shfl_xor(qsum, 16); qsum += __shfl_xor(qsum, 32);
      if (lane < 16) { unsafeAtomicAdd(&bn1s[col], ssum); unsafeAtomicAdd(&bn1q[col], qsum); }
    }
    gbar(cnt, gen, mode);

    {
      const int col = q * 128 + w * 16 + lr;
      for (int c = tid; c < H; c += NTHR) {
        float m = aload_f(&bn1s[c]) * (1.0f / B);
        float v = aload_f(&bn1q[c]) * (1.0f / B) - m * m;
        float s2_ = ga1[c] * rsqrtf(v + 1e-5f);
        sc[c] = s2_; sh[c] = be1[c] - m * s2_;
      }
      __syncthreads();
      f32x4 acc[4];
#pragma unroll
      for (int mi = 0; mi < 4; mi++) acc[mi] = (f32x4)(0.0f);
#pragma unroll
      for (int c = 0; c < 2; c++) {
        if (c) __syncthreads();
        for (int i = tid; i < 4096; i += NTHR) {
          int r = i >> 6, k4 = (i & 63) * 4, gk = c * 256 + k4;
          ushort4 gv = *(const ushort4*)&g1[(mb * 64 + r) * H + gk];
          ushort4 o;
          o.x = f2bf(fmaf(bf2f(gv.x), sc[gk + 0], sh[gk + 0]));
          o.y = f2bf(fmaf(bf2f(gv.y), sc[gk + 1], sh[gk + 1]));
          o.z = f2bf(fmaf(bf2f(gv.z), sc[gk + 2], sh[gk + 2]));
          o.w = f2bf(fmaf(bf2f(gv.w), sc[gk + 3], sh[gk + 3]));
          *(ushort4*)&smem[r * 264 + k4] = o;
        }
        __syncthreads();
#pragma unroll
        for (int ks = 0; ks < 8; ks++) {
          bf8 b = *(const bf8*)(w3t + col * H + c * 256 + ks * 32 + lg * 8);
#pragma unroll
          for (int mi = 0; mi < 4; mi++) {
            bf8 a = *(const bf8*)&smem[(mi * 16 + lr) * 264 + ks * 32 + lg * 8];
            acc[mi] = mfma16(a, b, acc[mi]);
          }
        }
      }
      float bb = b3[col], ssum = 0.0f, qsum = 0.0f;
#pragma unroll
      for (int mi = 0; mi < 4; mi++)
#pragma unroll
        for (int r = 0; r < 4; r++) {
          float v = gelu(acc[mi][r] + bb);
          g2h[(mb * 64 + mi * 16 + lg * 4 + r) * H + col] = f2bf(v);
          ssum += v; qsum += v * v;
        }
      ssum += __shfl_xor(ssum, 16); ssum += __shfl_xor(ssum, 32);
      qsum += __shfl_xor(qsum, 16); qsum += __shfl_xor(qsum, 32);
      if (lane < 16) { unsafeAtomicAdd(&bn2s[col], ssum); unsafeAtomicAdd(&bn2q[col], qsum); }
    }
    gbar(cnt, gen, mode);

    {
      ushort* at16 = smem;
      ushort* xt   = smem + 16 * 520;
      for (int c = tid; c < H; c += NTHR) {
        float m = aload_f(&bn2s[c]) * (1.0f / B);
        float v = aload_f(&bn2q[c]) * (1.0f / B) - m * m;
        float s2_ = ga2[c] * rsqrtf(v + 1e-5f);
        sc[c] = s2_; sh[c] = be2[c] - m * s2_;
      }
      __syncthreads();
      for (int i = tid; i < 2048; i += NTHR) {
        int r = i >> 7, k4 = (i & 127) * 4;
        ushort4 gv = *(const ushort4*)&g2h[(cbase + r) * H + k4];
        ushort4 o;
        o.x = f2bf(fmaf(bf2f(gv.x), sc[k4 + 0], sh[k4 + 0]));
        o.y = f2bf(fmaf(bf2f(gv.y), sc[k4 + 1], sh[k4 + 1]));
        o.z = f2bf(fmaf(bf2f(gv.z), sc[k4 + 2], sh[k4 + 2]));
        o.w = f2bf(fmaf(bf2f(gv.w), sc[k4 + 3], sh[k4 + 3]));
        *(ushort4*)&at16[r * 520 + k4] = o;
      }
      __syncthreads();

      const int col = w * 16 + lr;
      f32x4 acc = (f32x4)(0.0f);
#pragma unroll
      for (int ks = 0; ks < 16; ks++) {
        bf8 a = *(const bf8*)&at16[lr * 520 + ks * 32 + lg * 8];
        bf8 b = *(const bf8*)(w4t + col * H + ks * 32 + lg * 8);
        acc = mfma16(a, b, acc);
      }

      uint32_t k0, k1;
      step_keys(s, k0, k1);
      float zz[4] = {0, 0, 0, 0}, zw[4] = {0, 0, 0, 0};
      float tnext = (float)(s + 1) * dt;
      if (col < DD) {
        float bb = b4[col];
#pragma unroll
        for (int r = 0; r < 4; r++) {
          int row = lg * 4 + r, grow = cbase + row;
          float z = acc[r] + bb;
          uint32_t m = (uint32_t)grow * (uint32_t)DD + (uint32_t)col;
          float dW = 0.125f * jax_normal_from_bits(jax_bits(k0, k1, m));
          float xn = x[grow * DX + col] + 1.4142135623730951f * dW;
          x[grow * DX + col] = xn;
          xt[row * 136 + col] = f2bf(xn);
          zz[r] = z * z;
          zw[r] = z * dW;
        }
      } else {
#pragma unroll
        for (int r = 0; r < 4; r++)
          xt[(lg * 4 + r) * 136 + col] = (col == DX) ? f2bf(tnext) : (ushort)0;
      }
#pragma unroll
      for (int r = 0; r < 4; r++) {
        zz[r] += __shfl_xor(zz[r], 1); zz[r] += __shfl_xor(zz[r], 2);
        zz[r] += __shfl_xor(zz[r], 4); zz[r] += __shfl_xor(zz[r], 8);
        zw[r] += __shfl_xor(zw[r], 1); zw[r] += __shfl_xor(zw[r], 2);
        zw[r] += __shfl_xor(zw[r], 4); zw[r] += __shfl_xor(zw[r], 8);
      }
      if (lr == 0) {
#pragma unroll
        for (int r = 0; r < 4; r++) {
          ys1[w][lg * 4 + r] = zz[r];
          ys2[w][lg * 4 + r] = zw[r];
        }
      }
      __syncthreads();
      if (tid < 16) {
        float s1 = 0.0f, s2_ = 0.0f;
#pragma unroll
        for (int i = 0; i < 8; i++) { s1 += ys1[i][tid]; s2_ += ys2[i][tid]; }
        y[cbase + tid] += 0.5f * dt * s1 + s2_;
      }
      if (s < NSTEPS - 1)
        l1_sec(xt, w1t, b1, g2h, cbase, w, lr, lg);
    }
    if (s < NSTEPS - 1) gbar(cnt, gen, mode);
  }
}

// ================================================================

extern "C" void kernel_launch(void* const* d_in, const int* in_sizes, int n_in,
                              void* d_out, int out_size, void* d_ws, size_t ws_size,
                              hipStream_t stream)
{
  const float* y0  = (const float*)d_in[0];
  const float* W1  = (const float*)d_in[1];
  const float* b1  = (const float*)d_in[2];
  const float* W2  = (const float*)d_in[3];
  const float* b2  = (const float*)d_in[4];
  const float* W3  = (const float*)d_in[5];
  const float* b3  = (const float*)d_in[6];
  const float* W4  = (const float*)d_in[7];
  const float* b4  = (const float*)d_in[8];
  const float* ga1 = (const float*)d_in[9];
  const float* be1 = (const float*)d_in[10];
  const float* ga2 = (const float*)d_in[11];
  const float* be2 = (const float*)d_in[12];
  const float* x0  = (const float*)d_in[13];

  float* x = (float*)d_out;        // B*DX
  float* y = x + B * DX;           // B

  // chunked path sizing: fixed = bn + x_run + weights; per-step = g (in-place) + xs
  const size_t fixed_b = (size_t)NSTEPS * 4 * H * 4 + (size_t)B * DX * 4 +
                         (size_t)(H * KIN + H * H + H * H + N4 * H) * 2;
  const size_t per_b = (size_t)B * H * 2 + (size_t)B * KIN * 2;   // g + xs per step
  long smax = ((long)ws_size - (long)fixed_b) / (long)per_b;
  int S = (int)(smax < 64 ? smax : 64);

  if (S >= 1) {
    // ---------------- chunked step-parallel path ----------------
    float* bn    = (float*)d_ws;                       // NSTEPS*4*H
    float* x_run = bn + NSTEPS * 4 * H;                // B*DX
    ushort* w1t = (ushort*)(x_run + B * DX);
    ushort* w2t = w1t + H * KIN;
    ushort* w3t = w2t + H * H;
    ushort* w4t = w3t + H * H;
    ushort* g   = w4t + N4 * H;                        // S*B*H   (in-place)
    ushort* xs  = g + (size_t)S * B * H;               // S*B*KIN

    k_init_chunk<<<256, 256, 0, stream>>>(y0, x0, x_run, y, bn);
    k_prep<<<512, 256, 0, stream>>>(W1, W2, W3, W4, w1t, w2t, w3t, w4t);

    for (int s0 = 0; s0 < NSTEPS; s0 += S) {
      int Sc = (NSTEPS - s0 < S) ? (NSTEPS - s0) : S;
      k_xs<<<(B * KIN) / 256, 256, 0, stream>>>(x_run, xs, x, s0, Sc);
      kL12<<<Sc * 64, 512, 0, stream>>>(xs, w1t, b1, w2t, b2, g, bn, s0);
      kL3 <<<Sc * 64, 512, 0, stream>>>(g, bn, s0, ga1, be1, w3t, b3);
      kL4 <<<Sc * 128, 512, 0, stream>>>(g, bn, s0, ga2, be2, w4t, b4, y);
    }
  } else {
    // ---------------- round-9 cooperative fallback ----------------
    int*   bar = (int*)d_ws;
    float* bn  = (float*)d_ws + 32;
    ushort* ub  = (ushort*)(bn + NSTEPS * 4 * H);
    ushort* g1  = ub;
    ushort* g2h = g1 + B * H;
    ushort* w1t = g2h + B * H;
    ushort* w2t = w1t + H * KIN;
    ushort* w3t = w2t + H * H;
    ushort* w4t = w3t + H * H;

    k_init_coop<<<256, 256, 0, stream>>>(y0, x0, x, y, bn, bar);
    k_prep<<<512, 256, 0, stream>>>(W1, W2, W3, W4, w1t, w2t, w3t, w4t);

    void* args[] = {
      (void*)&w1t, (void*)&b1, (void*)&w2t, (void*)&b2,
      (void*)&w3t, (void*)&b3, (void*)&w4t, (void*)&b4,
      (void*)&ga1, (void*)&be1, (void*)&ga2, (void*)&be2,
      (void*)&g1, (void*)&g2h, (void*)&bn, (void*)&x, (void*)&y, (void*)&bar
    };
    hipLaunchCooperativeKernel((const void*)k_steps, dim3(NBLK), dim3(NTHR),
                               args, 0, stream);
  }
}

// Round 18
// 1432.916 us; speedup vs baseline: 1.3095x; 1.3095x over previous
//
#include <hip/hip_runtime.h>
#include <hip/hip_bf16.h>
#include <stdint.h>

#define B 4096
#define DX 100
#define H 512
#define DD 100
#define NSTEPS 64
#define KIN 128      // padded K for layer 1 (101 -> 128)
#define N4 128       // padded N for layer 4 (100 -> 128)
#define NBLK 256
#define NTHR 512

typedef short bf8 __attribute__((ext_vector_type(8)));    // 8 x bf16
typedef float f32x4 __attribute__((ext_vector_type(4)));  // MFMA C/D

__device__ __forceinline__ ushort f2bf(float f) {
  union { __hip_bfloat16 h; ushort u; } cv;
  cv.h = __float2bfloat16(f);          // hw v_cvt (RNE)
  return cv.u;
}
__device__ __forceinline__ float bf2f(ushort h) {
  return __uint_as_float((uint32_t)h << 16);
}
__device__ __forceinline__ f32x4 mfma16(bf8 a, bf8 b, f32x4 c) {
  return __builtin_amdgcn_mfma_f32_16x16x32_bf16(a, b, c, 0, 0, 0);
}

__device__ __forceinline__ int aload_i(int* p) {
  return __hip_atomic_load(p, __ATOMIC_RELAXED, __HIP_MEMORY_SCOPE_AGENT);
}
__device__ __forceinline__ float aload_f(const float* p) {
  return __hip_atomic_load((float*)p, __ATOMIC_RELAXED, __HIP_MEMORY_SCOPE_AGENT);
}

// ---------------- JAX threefry2x32 (20 rounds) ----------------
__device__ __forceinline__ void tf2x32(uint32_t k0, uint32_t k1,
                                       uint32_t x0, uint32_t x1,
                                       uint32_t& o0, uint32_t& o1)
{
  uint32_t ks2 = 0x1BD11BDAu ^ k0 ^ k1;
  x0 += k0; x1 += k1;
#define RND(r) { x0 += x1; x1 = (x1 << (r)) | (x1 >> (32 - (r))); x1 ^= x0; }
  RND(13) RND(15) RND(26) RND(6)   x0 += k1;  x1 += ks2 + 1u;
  RND(17) RND(29) RND(16) RND(24)  x0 += ks2; x1 += k0  + 2u;
  RND(13) RND(15) RND(26) RND(6)   x0 += k0;  x1 += k1  + 3u;
  RND(17) RND(29) RND(16) RND(24)  x0 += k1;  x1 += ks2 + 4u;
  RND(13) RND(15) RND(26) RND(6)   x0 += ks2; x1 += k0  + 5u;
#undef RND
  o0 = x0; o1 = x1;
}
// threefry_partitionable=True: split(key(42),64) -> key[s] = threefry((0,42),(0,s))
__device__ __forceinline__ void step_keys(int step, uint32_t& k0, uint32_t& k1)
{
  tf2x32(0u, 42u, 0u, (uint32_t)step, k0, k1);
}
// partitionable random_bits: counter (0,m), bits = o0 ^ o1
__device__ __forceinline__ uint32_t jax_bits(uint32_t k0, uint32_t k1, uint32_t m)
{
  uint32_t a, b;
  tf2x32(k0, k1, 0u, m, a, b);
  return a ^ b;
}

__device__ __forceinline__ float jax_normal_from_bits(uint32_t bits)
{
  float f = __uint_as_float((bits >> 9) | 0x3f800000u) - 1.0f;
  const float lo = -0.99999994f;
  float u = fmaxf(lo, f * 2.0f + lo);
  float w = -log1pf(-u * u);
  float p;
  if (w < 5.0f) {
    w -= 2.5f;
    p =          2.81022636e-08f;
    p = fmaf(p, w, 3.43273939e-07f);
    p = fmaf(p, w, -3.5233877e-06f);
    p = fmaf(p, w, -4.39150654e-06f);
    p = fmaf(p, w, 0.00021858087f);
    p = fmaf(p, w, -0.00125372503f);
    p = fmaf(p, w, -0.00417768164f);
    p = fmaf(p, w, 0.246640727f);
    p = fmaf(p, w, 1.50140941f);
  } else {
    w = sqrtf(w) - 3.0f;
    p =          -0.000200214257f;
    p = fmaf(p, w, 0.000100950558f);
    p = fmaf(p, w, 0.00134934322f);
    p = fmaf(p, w, -0.00367342844f);
    p = fmaf(p, w, 0.00573950773f);
    p = fmaf(p, w, -0.0076224613f);
    p = fmaf(p, w, 0.00943887047f);
    p = fmaf(p, w, 1.00167406f);
    p = fmaf(p, w, 2.83297682f);
  }
  return 1.4142135623730951f * (p * u);
}

// fast tanh-form GELU: max |err| vs exact erf-GELU ~1e-3 (<< bf16 activation noise)
__device__ __forceinline__ float gelu(float v)
{
  float v2 = v * v;
  float zin = fmaf(0.044715f * v2, v, v);               // v + 0.044715 v^3
  float z = fminf(1.5957691216057308f * zin, 80.0f);    // 2*sqrt(2/pi)*zin, clamped
  float e = __expf(z);                                   // hw exp
  float t = (e - 1.0f) * __builtin_amdgcn_rcpf(e + 1.0f);// tanh
  float hv = 0.5f * v;
  return fmaf(hv, t, hv);
}

// ---------------- prep: bf16 transposed weights (shared by both paths) ----------------
__global__ void k_prep(const float* __restrict__ W1, const float* __restrict__ W2,
                       const float* __restrict__ W3, const float* __restrict__ W4,
                       ushort* __restrict__ w1t, ushort* __restrict__ w2t,
                       ushort* __restrict__ w3t, ushort* __restrict__ w4t)
{
  int gid = blockIdx.x * blockDim.x + threadIdx.x;
  int stride = gridDim.x * blockDim.x;
  for (int i = gid; i < H * KIN; i += stride) {
    int c = i >> 7, k = i & (KIN - 1);
    w1t[i] = f2bf(k < 101 ? W1[k * H + c] : 0.0f);
  }
  for (int i = gid; i < H * H; i += stride) {
    int c = i >> 9, k = i & (H - 1);
    w2t[i] = f2bf(W2[k * H + c]);
    w3t[i] = f2bf(W3[k * H + c]);
  }
  for (int i = gid; i < N4 * H; i += stride) {
    int c = i >> 9, k = i & (H - 1);
    w4t[i] = f2bf(c < DD ? W4[k * DD + c] : 0.0f);
  }
}

// ================================================================
// ===================  CHUNKED STEP-PARALLEL PATH  ===============
// ================================================================

__global__ void k_init_chunk(const float* __restrict__ y0, const float* __restrict__ x0,
                             float* __restrict__ x_run, float* __restrict__ y,
                             float* __restrict__ bn)
{
  int gid = blockIdx.x * blockDim.x + threadIdx.x;
  int stride = gridDim.x * blockDim.x;
  for (int i = gid; i < B * DX; i += stride) x_run[i] = x0[i % DX];
  for (int i = gid; i < B; i += stride) y[i] = y0[0];
  for (int i = gid; i < NSTEPS * 4 * H; i += stride) bn[i] = 0.0f;
}

// RNG prefix: xs[t][row][0..127] bf16 for chunk steps; carries x_run; writes final x
__global__ void k_xs(float* __restrict__ x_run, ushort* __restrict__ xs,
                     float* __restrict__ xout, int s0, int Sc)
{
  int gid = blockIdx.x * blockDim.x + threadIdx.x;   // 4096*128 threads
  int row = gid >> 7, col = gid & 127;
  const float dt = 1.0f / NSTEPS;
  if (col < DX) {
    float xr = x_run[row * DX + col];
    uint32_t m = (uint32_t)(row * DD + col);
    for (int t = 0; t < Sc; ++t) {
      xs[t * (B * KIN) + row * KIN + col] = f2bf(xr);   // x_s BEFORE this step's dW
      uint32_t k0, k1;
      step_keys(s0 + t, k0, k1);
      float dW = 0.125f * jax_normal_from_bits(jax_bits(k0, k1, m));
      xr += 1.4142135623730951f * dW;
    }
    x_run[row * DX + col] = xr;
    if (s0 + Sc == NSTEPS) xout[row * DX + col] = xr;
  } else {
    for (int t = 0; t < Sc; ++t)
      xs[t * (B * KIN) + row * KIN + col] =
          (col == DX) ? f2bf((float)(s0 + t) * dt) : (ushort)0;
  }
}

// kL12: h1 = gelu(xs@W1+b1) recomputed in LDS (4 K-chunks of 128);
// g1 = gelu(h1@W2+b2); BN1 stats. grid Sc*128: mb=bid>>1 (64 rows), nb=bid&1.
__global__ __launch_bounds__(256, 4) void kL12(
    const ushort* __restrict__ xs, const ushort* __restrict__ w1t,
    const float* __restrict__ b1, const ushort* __restrict__ w2t,
    const float* __restrict__ b2, ushort* __restrict__ gb,
    float* __restrict__ bn, int s0)
{
  __shared__ ushort xt[64][136];
  __shared__ ushort at[64][136];
  const int tid = threadIdx.x;
  const int mb = blockIdx.x >> 1, nb = blockIdx.x & 1;
  const int base = mb * 64;
  float* bns = bn + (s0 + (mb >> 6)) * 4 * H;
  float* bnq = bns + H;
  const int w = tid >> 6, lane = tid & 63, lr = lane & 15, lg = lane >> 4;

  for (int i = tid; i < 64 * 16; i += 256) {   // 64 rows x 16 bf8
    int r = i >> 4, kk = (i & 15) * 8;
    *(bf8*)&xt[r][kk] = *(const bf8*)&xs[(size_t)(base + r) * KIN + kk];
  }
  __syncthreads();

  f32x4 acc[4][4];
#pragma unroll
  for (int mi = 0; mi < 4; mi++)
#pragma unroll
    for (int t = 0; t < 4; t++) acc[mi][t] = (f32x4)(0.0f);

#pragma unroll
  for (int c = 0; c < 4; c++) {
    if (c) __syncthreads();   // at consumed by GEMM2 of c-1
    // ---- GEMM1: h1 cols [c*128 + w*32, +32)
#pragma unroll
    for (int u = 0; u < 2; u++) {
      int hcol = c * 128 + w * 32 + u * 16 + lr;
      bf8 bfr[4];
#pragma unroll
      for (int ks = 0; ks < 4; ks++)
        bfr[ks] = *(const bf8*)(w1t + hcol * KIN + ks * 32 + lg * 8);
      f32x4 a1[4];
#pragma unroll
      for (int mi = 0; mi < 4; mi++) a1[mi] = (f32x4)(0.0f);
#pragma unroll
      for (int ks = 0; ks < 4; ks++) {
#pragma unroll
        for (int mi = 0; mi < 4; mi++) {
          bf8 a = *(const bf8*)&xt[mi * 16 + lr][ks * 32 + lg * 8];
          a1[mi] = mfma16(a, bfr[ks], a1[mi]);
        }
      }
      int lcol = w * 32 + u * 16 + lr;
      float bb = b1[c * 128 + lcol];
#pragma unroll
      for (int mi = 0; mi < 4; mi++)
#pragma unroll
        for (int r = 0; r < 4; r++)
          at[mi * 16 + lg * 4 + r][lcol] = f2bf(gelu(a1[mi][r] + bb));
    }
    __syncthreads();   // at (h1 chunk) ready
    // ---- GEMM2 partial: K slice [c*128, +128)
#pragma unroll
    for (int ks = 0; ks < 4; ks++) {
      bf8 af[4];
#pragma unroll
      for (int mi = 0; mi < 4; mi++)
        af[mi] = *(const bf8*)&at[mi * 16 + lr][ks * 32 + lg * 8];
#pragma unroll
      for (int t = 0; t < 4; t++) {
        int col = nb * 256 + w * 64 + t * 16 + lr;
        bf8 b = *(const bf8*)(w2t + col * H + c * 128 + ks * 32 + lg * 8);
#pragma unroll
        for (int mi = 0; mi < 4; mi++) acc[mi][t] = mfma16(af[mi], b, acc[mi][t]);
      }
    }
  }

#pragma unroll
  for (int t = 0; t < 4; t++) {
    int col = nb * 256 + w * 64 + t * 16 + lr;
    float bb = b2[col], s = 0.0f, q = 0.0f;
#pragma unroll
    for (int mi = 0; mi < 4; mi++)
#pragma unroll
      for (int r = 0; r < 4; r++) {
        float v = gelu(acc[mi][t][r] + bb);
        gb[(size_t)(base + mi * 16 + lg * 4 + r) * H + col] = f2bf(v);
        s += v; q += v * v;
      }
    s += __shfl_xor(s, 16); s += __shfl_xor(s, 32);
    q += __shfl_xor(q, 16); q += __shfl_xor(q, 32);
    if (lane < 16) { unsafeAtomicAdd(&bns[col], s); unsafeAtomicAdd(&bnq[col], q); }
  }
}

// kL3: n2 = BN1(g1); g2 = gelu(n2@W3+b3); BN2 stats. grid Sc*128, 4 K-chunks.
__global__ __launch_bounds__(256, 4) void kL3(
    const ushort* __restrict__ gb, float* __restrict__ bn, int s0,
    const float* __restrict__ gamma, const float* __restrict__ beta,
    const ushort* __restrict__ w3t, const float* __restrict__ b3,
    ushort* __restrict__ ga)
{
  __shared__ float sc[H], sh[H];
  __shared__ ushort at[64][136];
  const int tid = threadIdx.x;
  const int mb = blockIdx.x >> 1, nb = blockIdx.x & 1;
  const int base = mb * 64;
  float* bn1s = bn + (s0 + (mb >> 6)) * 4 * H;
  float* bn1q = bn1s + H;
  float* bn2s = bn1s + 2 * H;
  float* bn2q = bn1s + 3 * H;
  const int w = tid >> 6, lane = tid & 63, lr = lane & 15, lg = lane >> 4;

  for (int c = tid; c < H; c += 256) {
    float m = bn1s[c] * (1.0f / B);
    float v = bn1q[c] * (1.0f / B) - m * m;
    float s2_ = gamma[c] * rsqrtf(v + 1e-5f);
    sc[c] = s2_; sh[c] = beta[c] - m * s2_;
  }

  f32x4 acc[4][4];
#pragma unroll
  for (int mi = 0; mi < 4; mi++)
#pragma unroll
    for (int t = 0; t < 4; t++) acc[mi][t] = (f32x4)(0.0f);

#pragma unroll
  for (int c = 0; c < 4; c++) {
    __syncthreads();   // c=0: sc/sh ready; else: at consumed by GEMM of c-1
    for (int i = tid; i < 2048; i += 256) {         // 64 rows x 32 vec4
      int r = i >> 5, k4 = (i & 31) * 4, gk = c * 128 + k4;
      ushort4 gv = *(const ushort4*)&gb[(size_t)(base + r) * H + gk];
      ushort4 o;
      o.x = f2bf(fmaf(bf2f(gv.x), sc[gk + 0], sh[gk + 0]));
      o.y = f2bf(fmaf(bf2f(gv.y), sc[gk + 1], sh[gk + 1]));
      o.z = f2bf(fmaf(bf2f(gv.z), sc[gk + 2], sh[gk + 2]));
      o.w = f2bf(fmaf(bf2f(gv.w), sc[gk + 3], sh[gk + 3]));
      *(ushort4*)&at[r][k4] = o;
    }
    __syncthreads();
#pragma unroll
    for (int ks = 0; ks < 4; ks++) {
      bf8 af[4];
#pragma unroll
      for (int mi = 0; mi < 4; mi++)
        af[mi] = *(const bf8*)&at[mi * 16 + lr][ks * 32 + lg * 8];
#pragma unroll
      for (int t = 0; t < 4; t++) {
        int col = nb * 256 + w * 64 + t * 16 + lr;
        bf8 b = *(const bf8*)(w3t + col * H + c * 128 + ks * 32 + lg * 8);
#pragma unroll
        for (int mi = 0; mi < 4; mi++) acc[mi][t] = mfma16(af[mi], b, acc[mi][t]);
      }
    }
  }

#pragma unroll
  for (int t = 0; t < 4; t++) {
    int col = nb * 256 + w * 64 + t * 16 + lr;
    float bb = b3[col], s = 0.0f, q = 0.0f;
#pragma unroll
    for (int mi = 0; mi < 4; mi++)
#pragma unroll
      for (int r = 0; r < 4; r++) {
        float v = gelu(acc[mi][t][r] + bb);
        ga[(size_t)(base + mi * 16 + lg * 4 + r) * H + col] = f2bf(v);
        s += v; q += v * v;
      }
    s += __shfl_xor(s, 16); s += __shfl_xor(s, 32);
    q += __shfl_xor(q, 16); q += __shfl_xor(q, 32);
    if (lane < 16) { unsafeAtomicAdd(&bn2s[col], s); unsafeAtomicAdd(&bn2q[col], q); }
  }
}

// kL4: n3 = BN2(g2); z = n3@W4+b4; RNG recompute; y atomics.
// grid Sc*128, 512 thr: 32 rows per block.
__global__ __launch_bounds__(512, 4) void kL4(
    const ushort* __restrict__ ga, const float* __restrict__ bn, int s0,
    const float* __restrict__ gamma, const float* __restrict__ beta,
    const ushort* __restrict__ w4t, const float* __restrict__ b4,
    float* __restrict__ y)
{
  __shared__ float sc[H], sh[H];
  __shared__ ushort at[32 * 520];
  __shared__ float ys1[8][32], ys2[8][32];
  const int tid = threadIdx.x;
  const int sb = blockIdx.x >> 7;           // step within chunk
  const int s = s0 + sb;
  const int lb = (blockIdx.x & 127) * 32;   // row base within step's batch
  const int rbase = sb * B + lb;            // row base in chunk buffer
  const float dt = 1.0f / NSTEPS;
  const float* bn2s = bn + s * 4 * H + 2 * H;
  const float* bn2q = bn2s + H;

  for (int c = tid; c < H; c += 512) {
    float m = bn2s[c] * (1.0f / B);
    float v = bn2q[c] * (1.0f / B) - m * m;
    float s2_ = gamma[c] * rsqrtf(v + 1e-5f);
    sc[c] = s2_; sh[c] = beta[c] - m * s2_;
  }
  __syncthreads();
  for (int i = tid; i < 32 * 128; i += 512) {   // 32 rows x 128 vec4
    int r = i >> 7, k4 = (i & 127) * 4;
    ushort4 gv = *(const ushort4*)&ga[(size_t)(rbase + r) * H + k4];
    ushort4 o;
    o.x = f2bf(fmaf(bf2f(gv.x), sc[k4 + 0], sh[k4 + 0]));
    o.y = f2bf(fmaf(bf2f(gv.y), sc[k4 + 1], sh[k4 + 1]));
    o.z = f2bf(fmaf(bf2f(gv.z), sc[k4 + 2], sh[k4 + 2]));
    o.w = f2bf(fmaf(bf2f(gv.w), sc[k4 + 3], sh[k4 + 3]));
    *(ushort4*)&at[r * 520 + k4] = o;
  }
  __syncthreads();

  const int w = tid >> 6, lane = tid & 63, lr = lane & 15, lg = lane >> 4;
  const int col = w * 16 + lr;              // 0..127 (w4t zero-padded)
  f32x4 acc[2];
  acc[0] = (f32x4)(0.0f); acc[1] = (f32x4)(0.0f);
#pragma unroll
  for (int ks = 0; ks < 16; ks++) {
    bf8 b = *(const bf8*)(w4t + col * H + ks * 32 + lg * 8);
#pragma unroll
    for (int mi = 0; mi < 2; mi++) {
      bf8 a = *(const bf8*)&at[(mi * 16 + lr) * 520 + ks * 32 + lg * 8];
      acc[mi] = mfma16(a, b, acc[mi]);
    }
  }

  uint32_t k0, k1;
  step_keys(s, k0, k1);
#pragma unroll
  for (int mi = 0; mi < 2; mi++) {
    float zz[4] = {0, 0, 0, 0}, zw[4] = {0, 0, 0, 0};
    if (col < DD) {
      float bb = b4[col];
#pragma unroll
      for (int r = 0; r < 4; r++) {
        int lrow = lb + mi * 16 + lg * 4 + r;   // row within this step's batch
        float z = acc[mi][r] + bb;
        uint32_t m = (uint32_t)lrow * (uint32_t)DD + (uint32_t)col;
        float dW = 0.125f * jax_normal_from_bits(jax_bits(k0, k1, m));
        zz[r] = z * z;
        zw[r] = z * dW;
      }
    }
#pragma unroll
    for (int r = 0; r < 4; r++) {
      zz[r] += __shfl_xor(zz[r], 1); zz[r] += __shfl_xor(zz[r], 2);
      zz[r] += __shfl_xor(zz[r], 4); zz[r] += __shfl_xor(zz[r], 8);
      zw[r] += __shfl_xor(zw[r], 1); zw[r] += __shfl_xor(zw[r], 2);
      zw[r] += __shfl_xor(zw[r], 4); zw[r] += __shfl_xor(zw[r], 8);
    }
    if (lr == 0) {
#pragma unroll
      for (int r = 0; r < 4; r++) {
        ys1[w][mi * 16 + lg * 4 + r] = zz[r];
        ys2[w][mi * 16 + lg * 4 + r] = zw[r];
      }
    }
  }
  __syncthreads();
  if (tid < 32) {
    float s1 = 0.0f, s2_ = 0.0f;
#pragma unroll
    for (int i = 0; i < 8; i++) { s1 += ys1[i][tid]; s2_ += ys2[i][tid]; }
    unsafeAtomicAdd(&y[lb + tid], 0.5f * dt * s1 + s2_);
  }
}

// ================================================================
// =============  ROUND-9 COOPERATIVE FALLBACK PATH  ==============
// ================================================================

__device__ __forceinline__ void gbar(int* cnt, int* gen, int mode)
{
  if (mode) __builtin_amdgcn_fence(__ATOMIC_RELEASE, "agent");
  __syncthreads();
  if (threadIdx.x == 0) {
    int g = aload_i(gen);
    int a = __hip_atomic_fetch_add(cnt, 1, __ATOMIC_RELAXED, __HIP_MEMORY_SCOPE_AGENT);
    if (a == NBLK - 1) {
      __hip_atomic_store(cnt, 0, __ATOMIC_RELAXED, __HIP_MEMORY_SCOPE_AGENT);
      __hip_atomic_store(gen, g + 1, __ATOMIC_RELAXED, __HIP_MEMORY_SCOPE_AGENT);
    } else {
      while (aload_i(gen) == g) __builtin_amdgcn_s_sleep(2);
    }
  }
  __syncthreads();
  if (mode) __builtin_amdgcn_fence(__ATOMIC_ACQUIRE, "agent");
  else      asm volatile("buffer_inv" ::: "memory");
}

__global__ void k_init_coop(const float* __restrict__ y0, const float* __restrict__ x0,
                            float* __restrict__ x, float* __restrict__ y,
                            float* __restrict__ bn, int* __restrict__ bar)
{
  int gid = blockIdx.x * blockDim.x + threadIdx.x;
  int stride = gridDim.x * blockDim.x;
  for (int i = gid; i < B * DX; i += stride) x[i] = x0[i % DX];
  for (int i = gid; i < B; i += stride) y[i] = y0[0];
  for (int i = gid; i < NSTEPS * 4 * H; i += stride) bn[i] = 0.0f;
  if (gid < 32) bar[gid] = 0;
}

__device__ __forceinline__ void l1_sec(const ushort* xt, const ushort* __restrict__ w1t,
                                       const float* __restrict__ b1,
                                       ushort* __restrict__ h1g,
                                       int base, int w, int lr, int lg)
{
  f32x4 a1[4];
#pragma unroll
  for (int t = 0; t < 4; t++) a1[t] = (f32x4)(0.0f);
#pragma unroll
  for (int ks = 0; ks < 4; ks++) {
    bf8 a = *(const bf8*)&xt[lr * 136 + ks * 32 + lg * 8];
#pragma unroll
    for (int t = 0; t < 4; t++) {
      int cc = w * 64 + t * 16 + lr;
      bf8 bfr = *(const bf8*)(w1t + cc * KIN + ks * 32 + lg * 8);
      a1[t] = mfma16(a, bfr, a1[t]);
    }
  }
#pragma unroll
  for (int t = 0; t < 4; t++) {
    int cc = w * 64 + t * 16 + lr;
    float bb = b1[cc];
#pragma unroll
    for (int r = 0; r < 4; r++)
      h1g[(base + lg * 4 + r) * H + cc] = f2bf(gelu(a1[t][r] + bb));
  }
}

__global__ void __launch_bounds__(NTHR, 2) k_steps(
    const ushort* __restrict__ w1t, const float* __restrict__ b1,
    const ushort* __restrict__ w2t, const float* __restrict__ b2,
    const ushort* __restrict__ w3t, const float* __restrict__ b3,
    const ushort* __restrict__ w4t, const float* __restrict__ b4,
    const float* __restrict__ ga1, const float* __restrict__ be1,
    const float* __restrict__ ga2, const float* __restrict__ be2,
    ushort* __restrict__ g1, ushort* __restrict__ g2h,
    float* __restrict__ bn, float* __restrict__ x, float* __restrict__ y,
    int* __restrict__ bar)
{
  __shared__ ushort smem[64 * 264];
  __shared__ float sc[H], sh[H];
  __shared__ float ys1[8][16], ys2[8][16];
  __shared__ int dsh[2];

  const int tid = threadIdx.x;
  const int w = tid >> 6, lane = tid & 63, lr = lane & 15, lg = lane >> 4;
  const float dt = 1.0f / NSTEPS;
  int* cnt = bar; int* gen = bar + 1;
  int* bins = bar + 2;
  int* gcnt = bar + 18;

  int sgs, mode;
  {
    if (tid == 0) {
      uint32_t xcc = __builtin_amdgcn_s_getreg(20 | (31 << 11)) & 15u;
      int j = __hip_atomic_fetch_add(&bins[xcc], 1, __ATOMIC_RELAXED, __HIP_MEMORY_SCOPE_AGENT);
      dsh[0] = (int)xcc; dsh[1] = j;
    }
    gbar(cnt, gen, 1);
    if (tid == 0) {
      int ok = 1;
      for (int k = 0; k < 8; k++)  ok &= (aload_i(&bins[k]) == 32);
      for (int k = 8; k < 16; k++) ok &= (aload_i(&bins[k]) == 0);
      if (ok) { dsh[0] = dsh[0] * 32 + dsh[1]; dsh[1] = 0; }
      else {
        dsh[0] = __hip_atomic_fetch_add(gcnt, 1, __ATOMIC_RELAXED, __HIP_MEMORY_SCOPE_AGENT);
        dsh[1] = 1;
      }
    }
    __syncthreads();
    sgs = dsh[0]; mode = dsh[1];
  }
  const int mb = sgs >> 2, q = sgs & 3;
  const int cbase = sgs * 16;

  {
    ushort* xt = smem;
    for (int i = tid; i < 16 * KIN; i += NTHR) {
      int r = i >> 7, k = i & (KIN - 1);
      xt[r * 136 + k] = (k < DX) ? f2bf(x[(cbase + r) * DX + k]) : (ushort)0;
    }
    __syncthreads();
    l1_sec(xt, w1t, b1, g2h, cbase, w, lr, lg);
  }
  gbar(cnt, gen, mode);

  for (int s = 0; s < NSTEPS; ++s) {
    float* bn1s = bn + s * 4 * H;
    float* bn1q = bn1s + H;
    float* bn2s = bn1s + 2 * H;
    float* bn2q = bn1s + 3 * H;

    {
      const int col = q * 128 + w * 16 + lr;
      f32x4 acc[4];
#pragma unroll
      for (int mi = 0; mi < 4; mi++) acc[mi] = (f32x4)(0.0f);
#pragma unroll
      for (int c = 0; c < 2; c++) {
        if (c) __syncthreads();
        for (int i = tid; i < 2048; i += NTHR) {
          int r = i >> 5, kk = (i & 31) * 8;
          *(bf8*)&smem[r * 264 + kk] = *(const bf8*)&g2h[(mb * 64 + r) * H + c * 256 + kk];
        }
        __syncthreads();
#pragma unroll
        for (int ks = 0; ks < 8; ks++) {
          bf8 b = *(const bf8*)(w2t + col * H + c * 256 + ks * 32 + lg * 8);
#pragma unroll
          for (int mi = 0; mi < 4; mi++) {
            bf8 a = *(const bf8*)&smem[(mi * 16 + lr) * 264 + ks * 32 + lg * 8];
            acc[mi] = mfma16(a, b, acc[mi]);
          }
        }
      }
      float bb = b2[col], ssum = 0.0f, qsum = 0.0f;
#pragma unroll
      for (int mi = 0; mi < 4; mi++)
#pragma unroll
        for (int r = 0; r < 4; r++) {
          float v = gelu(acc[mi][r] + bb);
          g1[(mb * 64 + mi * 16 + lg * 4 + r) * H + col] = f2bf(v);
          ssum += v; qsum += v * v;
        }
      ssum += __shfl_xor(ssum, 16); ssum += __shfl_xor(ssum, 32);
      qsum += __shfl_xor(qsum, 16); qsum += __shfl_xor(qsum, 32);
      if (lane < 16) { unsafeAtomicAdd(&bn1s[col], ssum); unsafeAtomicAdd(&bn1q[col], qsum); }
    }
    gbar(cnt, gen, mode);

    {
      const int col = q * 128 + w * 16 + lr;
      for (int c = tid; c < H; c += NTHR) {
        float m = aload_f(&bn1s[c]) * (1.0f / B);
        float v = aload_f(&bn1q[c]) * (1.0f / B) - m * m;
        float s2_ = ga1[c] * rsqrtf(v + 1e-5f);
        sc[c] = s2_; sh[c] = be1[c] - m * s2_;
      }
      __syncthreads();
      f32x4 acc[4];
#pragma unroll
      for (int mi = 0; mi < 4; mi++) acc[mi] = (f32x4)(0.0f);
#pragma unroll
      for (int c = 0; c < 2; c++) {
        if (c) __syncthreads();
        for (int i = tid; i < 4096; i += NTHR) {
          int r = i >> 6, k4 = (i & 63) * 4, gk = c * 256 + k4;
          ushort4 gv = *(const ushort4*)&g1[(mb * 64 + r) * H + gk];
          ushort4 o;
          o.x = f2bf(fmaf(bf2f(gv.x), sc[gk + 0], sh[gk + 0]));
          o.y = f2bf(fmaf(bf2f(gv.y), sc[gk + 1], sh[gk + 1]));
          o.z = f2bf(fmaf(bf2f(gv.z), sc[gk + 2], sh[gk + 2]));
          o.w = f2bf(fmaf(bf2f(gv.w), sc[gk + 3], sh[gk + 3]));
          *(ushort4*)&smem[r * 264 + k4] = o;
        }
        __syncthreads();
#pragma unroll
        for (int ks = 0; ks < 8; ks++) {
          bf8 b = *(const bf8*)(w3t + col * H + c * 256 + ks * 32 + lg * 8);
#pragma unroll
          for (int mi = 0; mi < 4; mi++) {
            bf8 a = *(const bf8*)&smem[(mi * 16 + lr) * 264 + ks * 32 + lg * 8];
            acc[mi] = mfma16(a, b, acc[mi]);
          }
        }
      }
      float bb = b3[col], ssum = 0.0f, qsum = 0.0f;
#pragma unroll
      for (int mi = 0; mi < 4; mi++)
#pragma unroll
        for (int r = 0; r < 4; r++) {
          float v = gelu(acc[mi][r] + bb);
          g2h[(mb * 64 + mi * 16 + lg * 4 + r) * H + col] = f2bf(v);
          ssum += v; qsum += v * v;
        }
      ssum += __shfl_xor(ssum, 16); ssum += __shfl_xor(ssum, 32);
      qsum += __shfl_xor(qsum, 16); qsum += __shfl_xor(qsum, 32);
      if (lane < 16) { unsafeAtomicAdd(&bn2s[col], ssum); unsafeAtomicAdd(&bn2q[col], qsum); }
    }
    gbar(cnt, gen, mode);

    {
      ushort* at16 = smem;
      ushort* xt   = smem + 16 * 520;
      for (int c = tid; c < H; c += NTHR) {
        float m = aload_f(&bn2s[c]) * (1.0f / B);
        float v = aload_f(&bn2q[c]) * (1.0f / B) - m * m;
        float s2_ = ga2[c] * rsqrtf(v + 1e-5f);
        sc[c] = s2_; sh[c] = be2[c] - m * s2_;
      }
      __syncthreads();
      for (int i = tid; i < 2048; i += NTHR) {
        int r = i >> 7, k4 = (i & 127) * 4;
        ushort4 gv = *(const ushort4*)&g2h[(cbase + r) * H + k4];
        ushort4 o;
        o.x = f2bf(fmaf(bf2f(gv.x), sc[k4 + 0], sh[k4 + 0]));
        o.y = f2bf(fmaf(bf2f(gv.y), sc[k4 + 1], sh[k4 + 1]));
        o.z = f2bf(fmaf(bf2f(gv.z), sc[k4 + 2], sh[k4 + 2]));
        o.w = f2bf(fmaf(bf2f(gv.w), sc[k4 + 3], sh[k4 + 3]));
        *(ushort4*)&at16[r * 520 + k4] = o;
      }
      __syncthreads();

      const int col = w * 16 + lr;
      f32x4 acc = (f32x4)(0.0f);
#pragma unroll
      for (int ks = 0; ks < 16; ks++) {
        bf8 a = *(const bf8*)&at16[lr * 520 + ks * 32 + lg * 8];
        bf8 b = *(const bf8*)(w4t + col * H + ks * 32 + lg * 8);
        acc = mfma16(a, b, acc);
      }

      uint32_t k0, k1;
      step_keys(s, k0, k1);
      float zz[4] = {0, 0, 0, 0}, zw[4] = {0, 0, 0, 0};
      float tnext = (float)(s + 1) * dt;
      if (col < DD) {
        float bb = b4[col];
#pragma unroll
        for (int r = 0; r < 4; r++) {
          int row = lg * 4 + r, grow = cbase + row;
          float z = acc[r] + bb;
          uint32_t m = (uint32_t)grow * (uint32_t)DD + (uint32_t)col;
          float dW = 0.125f * jax_normal_from_bits(jax_bits(k0, k1, m));
          float xn = x[grow * DX + col] + 1.4142135623730951f * dW;
          x[grow * DX + col] = xn;
          xt[row * 136 + col] = f2bf(xn);
          zz[r] = z * z;
          zw[r] = z * dW;
        }
      } else {
#pragma unroll
        for (int r = 0; r < 4; r++)
          xt[(lg * 4 + r) * 136 + col] = (col == DX) ? f2bf(tnext) : (ushort)0;
      }
#pragma unroll
      for (int r = 0; r < 4; r++) {
        zz[r] += __shfl_xor(zz[r], 1); zz[r] += __shfl_xor(zz[r], 2);
        zz[r] += __shfl_xor(zz[r], 4); zz[r] += __shfl_xor(zz[r], 8);
        zw[r] += __shfl_xor(zw[r], 1); zw[r] += __shfl_xor(zw[r], 2);
        zw[r] += __shfl_xor(zw[r], 4); zw[r] += __shfl_xor(zw[r], 8);
      }
      if (lr == 0) {
#pragma unroll
        for (int r = 0; r < 4; r++) {
          ys1[w][lg * 4 + r] = zz[r];
          ys2[w][lg * 4 + r] = zw[r];
        }
      }
      __syncthreads();
      if (tid < 16) {
        float s1 = 0.0f, s2_ = 0.0f;
#pragma unroll
        for (int i = 0; i < 8; i++) { s1 += ys1[i][tid]; s2_ += ys2[i][tid]; }
        y[cbase + tid] += 0.5f * dt * s1 + s2_;
      }
      if (s < NSTEPS - 1)
        l1_sec(xt, w1t, b1, g2h, cbase, w, lr, lg);
    }
    if (s < NSTEPS - 1) gbar(cnt, gen, mode);
  }
}

// ================================================================

extern "C" void kernel_launch(void* const* d_in, const int* in_sizes, int n_in,
                              void* d_out, int out_size, void* d_ws, size_t ws_size,
                              hipStream_t stream)
{
  const float* y0  = (const float*)d_in[0];
  const float* W1  = (const float*)d_in[1];
  const float* b1  = (const float*)d_in[2];
  const float* W2  = (const float*)d_in[3];
  const float* b2  = (const float*)d_in[4];
  const float* W3  = (const float*)d_in[5];
  const float* b3  = (const float*)d_in[6];
  const float* W4  = (const float*)d_in[7];
  const float* b4  = (const float*)d_in[8];
  const float* ga1 = (const float*)d_in[9];
  const float* be1 = (const float*)d_in[10];
  const float* ga2 = (const float*)d_in[11];
  const float* be2 = (const float*)d_in[12];
  const float* x0  = (const float*)d_in[13];

  float* x = (float*)d_out;        // B*DX
  float* y = x + B * DX;           // B

  // chunked path sizing: fixed = bn + x_run + weights; per-step = ga + gb
  const size_t fixed_b = (size_t)NSTEPS * 4 * H * 4 + (size_t)B * DX * 4 +
                         (size_t)(H * KIN + H * H + H * H + N4 * H) * 2;
  const size_t per_b = (size_t)B * H * 2 * 2;    // ga + gb per step
  long smax = ((long)ws_size - (long)fixed_b) / (long)per_b;
  int S = (int)(smax < 64 ? smax : 64);

  if (S >= 1) {
    // ---------------- chunked step-parallel path ----------------
    float* bn    = (float*)d_ws;                       // NSTEPS*4*H
    float* x_run = bn + NSTEPS * 4 * H;                // B*DX
    ushort* w1t = (ushort*)(x_run + B * DX);
    ushort* w2t = w1t + H * KIN;
    ushort* w3t = w2t + H * H;
    ushort* w4t = w3t + H * H;
    ushort* ga  = w4t + N4 * H;                        // S*B*H (xs at its front)
    ushort* gb  = ga + (size_t)S * B * H;              // S*B*H
    ushort* xs  = ga;   // xs consumed by kL12 before kL3 overwrites ga

    k_init_chunk<<<256, 256, 0, stream>>>(y0, x0, x_run, y, bn);
    k_prep<<<512, 256, 0, stream>>>(W1, W2, W3, W4, w1t, w2t, w3t, w4t);

    for (int s0 = 0; s0 < NSTEPS; s0 += S) {
      int Sc = (NSTEPS - s0 < S) ? (NSTEPS - s0) : S;
      k_xs<<<(B * KIN) / 256, 256, 0, stream>>>(x_run, xs, x, s0, Sc);
      kL12<<<Sc * 128, 256, 0, stream>>>(xs, w1t, b1, w2t, b2, gb, bn, s0);
      kL3 <<<Sc * 128, 256, 0, stream>>>(gb, bn, s0, ga1, be1, w3t, b3, ga);
      kL4 <<<Sc * 128, 512, 0, stream>>>(ga, bn, s0, ga2, be2, w4t, b4, y);
    }
  } else {
    // ---------------- round-9 cooperative fallback ----------------
    int*   bar = (int*)d_ws;
    float* bn  = (float*)d_ws + 32;
    ushort* ub  = (ushort*)(bn + NSTEPS * 4 * H);
    ushort* g1  = ub;
    ushort* g2h = g1 + B * H;
    ushort* w1t = g2h + B * H;
    ushort* w2t = w1t + H * KIN;
    ushort* w3t = w2t + H * H;
    ushort* w4t = w3t + H * H;

    k_init_coop<<<256, 256, 0, stream>>>(y0, x0, x, y, bn, bar);
    k_prep<<<512, 256, 0, stream>>>(W1, W2, W3, W4, w1t, w2t, w3t, w4t);

    void* args[] = {
      (void*)&w1t, (void*)&b1, (void*)&w2t, (void*)&b2,
      (void*)&w3t, (void*)&b3, (void*)&w4t, (void*)&b4,
      (void*)&ga1, (void*)&be1, (void*)&ga2, (void*)&be2,
      (void*)&g1, (void*)&g2h, (void*)&bn, (void*)&x, (void*)&y, (void*)&bar
    };
    hipLaunchCooperativeKernel((const void*)k_steps, dim3(NBLK), dim3(NTHR),
                               args, 0, stream);
  }
}

// Round 19
// 1349.339 us; speedup vs baseline: 1.3906x; 1.0619x over previous
//
#include <hip/hip_runtime.h>
#include <hip/hip_bf16.h>
#include <stdint.h>

#define B 4096
#define DX 100
#define H 512
#define DD 100
#define NSTEPS 64
#define KIN 128      // padded K for layer 1 (101 -> 128)
#define N4 128       // padded N for layer 4 (100 -> 128)
#define NBLK 256
#define NTHR 512

typedef short bf8 __attribute__((ext_vector_type(8)));    // 8 x bf16
typedef float f32x4 __attribute__((ext_vector_type(4)));  // MFMA C/D

__device__ __forceinline__ ushort f2bf(float f) {
  union { __hip_bfloat16 h; ushort u; } cv;
  cv.h = __float2bfloat16(f);          // hw v_cvt (RNE)
  return cv.u;
}
__device__ __forceinline__ float bf2f(ushort h) {
  return __uint_as_float((uint32_t)h << 16);
}
__device__ __forceinline__ f32x4 mfma16(bf8 a, bf8 b, f32x4 c) {
  return __builtin_amdgcn_mfma_f32_16x16x32_bf16(a, b, c, 0, 0, 0);
}

__device__ __forceinline__ int aload_i(int* p) {
  return __hip_atomic_load(p, __ATOMIC_RELAXED, __HIP_MEMORY_SCOPE_AGENT);
}
__device__ __forceinline__ float aload_f(const float* p) {
  return __hip_atomic_load((float*)p, __ATOMIC_RELAXED, __HIP_MEMORY_SCOPE_AGENT);
}

// ---------------- JAX threefry2x32 (20 rounds) ----------------
__device__ __forceinline__ void tf2x32(uint32_t k0, uint32_t k1,
                                       uint32_t x0, uint32_t x1,
                                       uint32_t& o0, uint32_t& o1)
{
  uint32_t ks2 = 0x1BD11BDAu ^ k0 ^ k1;
  x0 += k0; x1 += k1;
#define RND(r) { x0 += x1; x1 = (x1 << (r)) | (x1 >> (32 - (r))); x1 ^= x0; }
  RND(13) RND(15) RND(26) RND(6)   x0 += k1;  x1 += ks2 + 1u;
  RND(17) RND(29) RND(16) RND(24)  x0 += ks2; x1 += k0  + 2u;
  RND(13) RND(15) RND(26) RND(6)   x0 += k0;  x1 += k1  + 3u;
  RND(17) RND(29) RND(16) RND(24)  x0 += k1;  x1 += ks2 + 4u;
  RND(13) RND(15) RND(26) RND(6)   x0 += ks2; x1 += k0  + 5u;
#undef RND
  o0 = x0; o1 = x1;
}
// threefry_partitionable=True: split(key(42),64) -> key[s] = threefry((0,42),(0,s))
__device__ __forceinline__ void step_keys(int step, uint32_t& k0, uint32_t& k1)
{
  tf2x32(0u, 42u, 0u, (uint32_t)step, k0, k1);
}
// partitionable random_bits: counter (0,m), bits = o0 ^ o1
__device__ __forceinline__ uint32_t jax_bits(uint32_t k0, uint32_t k1, uint32_t m)
{
  uint32_t a, b;
  tf2x32(k0, k1, 0u, m, a, b);
  return a ^ b;
}

__device__ __forceinline__ float jax_normal_from_bits(uint32_t bits)
{
  float f = __uint_as_float((bits >> 9) | 0x3f800000u) - 1.0f;
  const float lo = -0.99999994f;
  float u = fmaxf(lo, f * 2.0f + lo);
  float w = -log1pf(-u * u);
  float p;
  if (w < 5.0f) {
    w -= 2.5f;
    p =          2.81022636e-08f;
    p = fmaf(p, w, 3.43273939e-07f);
    p = fmaf(p, w, -3.5233877e-06f);
    p = fmaf(p, w, -4.39150654e-06f);
    p = fmaf(p, w, 0.00021858087f);
    p = fmaf(p, w, -0.00125372503f);
    p = fmaf(p, w, -0.00417768164f);
    p = fmaf(p, w, 0.246640727f);
    p = fmaf(p, w, 1.50140941f);
  } else {
    w = sqrtf(w) - 3.0f;
    p =          -0.000200214257f;
    p = fmaf(p, w, 0.000100950558f);
    p = fmaf(p, w, 0.00134934322f);
    p = fmaf(p, w, -0.00367342844f);
    p = fmaf(p, w, 0.00573950773f);
    p = fmaf(p, w, -0.0076224613f);
    p = fmaf(p, w, 0.00943887047f);
    p = fmaf(p, w, 1.00167406f);
    p = fmaf(p, w, 2.83297682f);
  }
  return 1.4142135623730951f * (p * u);
}

// fast tanh-form GELU: max |err| vs exact erf-GELU ~1e-3 (<< bf16 activation noise)
__device__ __forceinline__ float gelu(float v)
{
  float v2 = v * v;
  float zin = fmaf(0.044715f * v2, v, v);               // v + 0.044715 v^3
  float z = fminf(1.5957691216057308f * zin, 80.0f);    // 2*sqrt(2/pi)*zin, clamped
  float e = __expf(z);                                   // hw exp
  float t = (e - 1.0f) * __builtin_amdgcn_rcpf(e + 1.0f);// tanh
  float hv = 0.5f * v;
  return fmaf(hv, t, hv);
}

// ---------------- prep: bf16 transposed weights (shared by both paths) ----------------
__global__ void k_prep(const float* __restrict__ W1, const float* __restrict__ W2,
                       const float* __restrict__ W3, const float* __restrict__ W4,
                       ushort* __restrict__ w1t, ushort* __restrict__ w2t,
                       ushort* __restrict__ w3t, ushort* __restrict__ w4t)
{
  int gid = blockIdx.x * blockDim.x + threadIdx.x;
  int stride = gridDim.x * blockDim.x;
  for (int i = gid; i < H * KIN; i += stride) {
    int c = i >> 7, k = i & (KIN - 1);
    w1t[i] = f2bf(k < 101 ? W1[k * H + c] : 0.0f);
  }
  for (int i = gid; i < H * H; i += stride) {
    int c = i >> 9, k = i & (H - 1);
    w2t[i] = f2bf(W2[k * H + c]);
    w3t[i] = f2bf(W3[k * H + c]);
  }
  for (int i = gid; i < N4 * H; i += stride) {
    int c = i >> 9, k = i & (H - 1);
    w4t[i] = f2bf(c < DD ? W4[k * DD + c] : 0.0f);
  }
}

// ================================================================
// ===================  CHUNKED STEP-PARALLEL PATH  ===============
// ================================================================

__global__ void k_init_chunk(const float* __restrict__ y0, const float* __restrict__ x0,
                             float* __restrict__ x_run, float* __restrict__ y,
                             float* __restrict__ bn)
{
  int gid = blockIdx.x * blockDim.x + threadIdx.x;
  int stride = gridDim.x * blockDim.x;
  for (int i = gid; i < B * DX; i += stride) x_run[i] = x0[i % DX];
  for (int i = gid; i < B; i += stride) y[i] = y0[0];
  for (int i = gid; i < NSTEPS * 4 * H; i += stride) bn[i] = 0.0f;
}

// RNG prefix: xs[t][row][0..127] bf16 for chunk steps; carries x_run; writes final x
__global__ void k_xs(float* __restrict__ x_run, ushort* __restrict__ xs,
                     float* __restrict__ xout, int s0, int Sc)
{
  int gid = blockIdx.x * blockDim.x + threadIdx.x;   // 4096*128 threads
  int row = gid >> 7, col = gid & 127;
  const float dt = 1.0f / NSTEPS;
  if (col < DX) {
    float xr = x_run[row * DX + col];
    uint32_t m = (uint32_t)(row * DD + col);
    for (int t = 0; t < Sc; ++t) {
      xs[t * (B * KIN) + row * KIN + col] = f2bf(xr);   // x_s BEFORE this step's dW
      uint32_t k0, k1;
      step_keys(s0 + t, k0, k1);
      float dW = 0.125f * jax_normal_from_bits(jax_bits(k0, k1, m));
      xr += 1.4142135623730951f * dW;
    }
    x_run[row * DX + col] = xr;
    if (s0 + Sc == NSTEPS) xout[row * DX + col] = xr;
  } else {
    for (int t = 0; t < Sc; ++t)
      xs[t * (B * KIN) + row * KIN + col] =
          (col == DX) ? f2bf((float)(s0 + t) * dt) : (ushort)0;
  }
}

// kL12 (r18 variant): h1 = gelu(xs@W1+b1) in LDS (4 K-chunks of 128);
// g1 = gelu(h1@W2+b2); BN1 stats. grid Sc*128: mb=bid>>1 (64 rows), nb=bid&1.
__global__ __launch_bounds__(256, 4) void kL12(
    const ushort* __restrict__ xs, const ushort* __restrict__ w1t,
    const float* __restrict__ b1, const ushort* __restrict__ w2t,
    const float* __restrict__ b2, ushort* __restrict__ gb,
    float* __restrict__ bn, int s0)
{
  __shared__ ushort xt[64][136];
  __shared__ ushort at[64][136];
  const int tid = threadIdx.x;
  const int mb = blockIdx.x >> 1, nb = blockIdx.x & 1;
  const int base = mb * 64;
  float* bns = bn + (s0 + (mb >> 6)) * 4 * H;
  float* bnq = bns + H;
  const int w = tid >> 6, lane = tid & 63, lr = lane & 15, lg = lane >> 4;

  for (int i = tid; i < 64 * 16; i += 256) {   // 64 rows x 16 bf8
    int r = i >> 4, kk = (i & 15) * 8;
    *(bf8*)&xt[r][kk] = *(const bf8*)&xs[(size_t)(base + r) * KIN + kk];
  }
  __syncthreads();

  f32x4 acc[4][4];
#pragma unroll
  for (int mi = 0; mi < 4; mi++)
#pragma unroll
    for (int t = 0; t < 4; t++) acc[mi][t] = (f32x4)(0.0f);

#pragma unroll
  for (int c = 0; c < 4; c++) {
    if (c) __syncthreads();   // at consumed by GEMM2 of c-1
    // ---- GEMM1: h1 cols [c*128 + w*32, +32)
#pragma unroll
    for (int u = 0; u < 2; u++) {
      int hcol = c * 128 + w * 32 + u * 16 + lr;
      bf8 bfr[4];
#pragma unroll
      for (int ks = 0; ks < 4; ks++)
        bfr[ks] = *(const bf8*)(w1t + hcol * KIN + ks * 32 + lg * 8);
      f32x4 a1[4];
#pragma unroll
      for (int mi = 0; mi < 4; mi++) a1[mi] = (f32x4)(0.0f);
#pragma unroll
      for (int ks = 0; ks < 4; ks++) {
#pragma unroll
        for (int mi = 0; mi < 4; mi++) {
          bf8 a = *(const bf8*)&xt[mi * 16 + lr][ks * 32 + lg * 8];
          a1[mi] = mfma16(a, bfr[ks], a1[mi]);
        }
      }
      int lcol = w * 32 + u * 16 + lr;
      float bb = b1[c * 128 + lcol];
#pragma unroll
      for (int mi = 0; mi < 4; mi++)
#pragma unroll
        for (int r = 0; r < 4; r++)
          at[mi * 16 + lg * 4 + r][lcol] = f2bf(gelu(a1[mi][r] + bb));
    }
    __syncthreads();   // at (h1 chunk) ready
    // ---- GEMM2 partial: K slice [c*128, +128)
#pragma unroll
    for (int ks = 0; ks < 4; ks++) {
      bf8 af[4];
#pragma unroll
      for (int mi = 0; mi < 4; mi++)
        af[mi] = *(const bf8*)&at[mi * 16 + lr][ks * 32 + lg * 8];
#pragma unroll
      for (int t = 0; t < 4; t++) {
        int col = nb * 256 + w * 64 + t * 16 + lr;
        bf8 b = *(const bf8*)(w2t + col * H + c * 128 + ks * 32 + lg * 8);
#pragma unroll
        for (int mi = 0; mi < 4; mi++) acc[mi][t] = mfma16(af[mi], b, acc[mi][t]);
      }
    }
  }

#pragma unroll
  for (int t = 0; t < 4; t++) {
    int col = nb * 256 + w * 64 + t * 16 + lr;
    float bb = b2[col], s = 0.0f, q = 0.0f;
#pragma unroll
    for (int mi = 0; mi < 4; mi++)
#pragma unroll
      for (int r = 0; r < 4; r++) {
        float v = gelu(acc[mi][t][r] + bb);
        gb[(size_t)(base + mi * 16 + lg * 4 + r) * H + col] = f2bf(v);
        s += v; q += v * v;
      }
    s += __shfl_xor(s, 16); s += __shfl_xor(s, 32);
    q += __shfl_xor(q, 16); q += __shfl_xor(q, 32);
    if (lane < 16) { unsafeAtomicAdd(&bns[col], s); unsafeAtomicAdd(&bnq[col], q); }
  }
}

// kL3 (r12 variant): n2 = BN1(g1); g2 = gelu(n2@W3+b3); BN2 stats.
// grid Sc*128, 2 K-chunks of 256, at[64][264].
__global__ __launch_bounds__(256, 3) void kL3(
    const ushort* __restrict__ gb, float* __restrict__ bn, int s0,
    const float* __restrict__ gamma, const float* __restrict__ beta,
    const ushort* __restrict__ w3t, const float* __restrict__ b3,
    ushort* __restrict__ ga)
{
  __shared__ float sc[H], sh[H];
  __shared__ ushort at[64][264];
  const int tid = threadIdx.x;
  const int mb = blockIdx.x >> 1, nb = blockIdx.x & 1;
  const int base = mb * 64;
  float* bn1s = bn + (s0 + (mb >> 6)) * 4 * H;
  float* bn1q = bn1s + H;
  float* bn2s = bn1s + 2 * H;
  float* bn2q = bn1s + 3 * H;
  const int w = tid >> 6, lane = tid & 63, lr = lane & 15, lg = lane >> 4;

  for (int c = tid; c < H; c += 256) {
    float m = bn1s[c] * (1.0f / B);
    float v = bn1q[c] * (1.0f / B) - m * m;
    float s2_ = gamma[c] * rsqrtf(v + 1e-5f);
    sc[c] = s2_; sh[c] = beta[c] - m * s2_;
  }

  f32x4 acc[4][4];
#pragma unroll
  for (int mi = 0; mi < 4; mi++)
#pragma unroll
    for (int t = 0; t < 4; t++) acc[mi][t] = (f32x4)(0.0f);

#pragma unroll
  for (int c = 0; c < 2; c++) {
    __syncthreads();   // c=0: sc/sh ready; c=1: at consumed
    for (int i = tid; i < 4096; i += 256) {         // 64 rows x 64 vec4
      int r = i >> 6, k4 = (i & 63) * 4, gk = c * 256 + k4;
      ushort4 gv = *(const ushort4*)&gb[(size_t)(base + r) * H + gk];
      ushort4 o;
      o.x = f2bf(fmaf(bf2f(gv.x), sc[gk + 0], sh[gk + 0]));
      o.y = f2bf(fmaf(bf2f(gv.y), sc[gk + 1], sh[gk + 1]));
      o.z = f2bf(fmaf(bf2f(gv.z), sc[gk + 2], sh[gk + 2]));
      o.w = f2bf(fmaf(bf2f(gv.w), sc[gk + 3], sh[gk + 3]));
      *(ushort4*)&at[r][k4] = o;
    }
    __syncthreads();
#pragma unroll
    for (int ks = 0; ks < 8; ks++) {
      bf8 af[4];
#pragma unroll
      for (int mi = 0; mi < 4; mi++)
        af[mi] = *(const bf8*)&at[mi * 16 + lr][ks * 32 + lg * 8];
#pragma unroll
      for (int t = 0; t < 4; t++) {
        int col = nb * 256 + w * 64 + t * 16 + lr;
        bf8 b = *(const bf8*)(w3t + col * H + c * 256 + ks * 32 + lg * 8);
#pragma unroll
        for (int mi = 0; mi < 4; mi++) acc[mi][t] = mfma16(af[mi], b, acc[mi][t]);
      }
    }
  }

#pragma unroll
  for (int t = 0; t < 4; t++) {
    int col = nb * 256 + w * 64 + t * 16 + lr;
    float bb = b3[col], s = 0.0f, q = 0.0f;
#pragma unroll
    for (int mi = 0; mi < 4; mi++)
#pragma unroll
      for (int r = 0; r < 4; r++) {
        float v = gelu(acc[mi][t][r] + bb);
        ga[(size_t)(base + mi * 16 + lg * 4 + r) * H + col] = f2bf(v);
        s += v; q += v * v;
      }
    s += __shfl_xor(s, 16); s += __shfl_xor(s, 32);
    q += __shfl_xor(q, 16); q += __shfl_xor(q, 32);
    if (lane < 16) { unsafeAtomicAdd(&bn2s[col], s); unsafeAtomicAdd(&bn2q[col], q); }
  }
}

// kL4 (r12 variant + occupancy fix): n3 = BN2(g2); z = n3@W4+b4; RNG; y atomics.
// grid Sc*128, 512 thr: 32 rows per block.
__global__ __launch_bounds__(512, 4) void kL4(
    const ushort* __restrict__ ga, const float* __restrict__ bn, int s0,
    const float* __restrict__ gamma, const float* __restrict__ beta,
    const ushort* __restrict__ w4t, const float* __restrict__ b4,
    float* __restrict__ y)
{
  __shared__ float sc[H], sh[H];
  __shared__ ushort at[32 * 520];
  __shared__ float ys1[8][32], ys2[8][32];
  const int tid = threadIdx.x;
  const int sb = blockIdx.x >> 7;           // step within chunk
  const int s = s0 + sb;
  const int lb = (blockIdx.x & 127) * 32;   // row base within step's batch
  const int rbase = sb * B + lb;            // row base in chunk buffer
  const float dt = 1.0f / NSTEPS;
  const float* bn2s = bn + s * 4 * H + 2 * H;
  const float* bn2q = bn2s + H;

  for (int c = tid; c < H; c += 512) {
    float m = bn2s[c] * (1.0f / B);
    float v = bn2q[c] * (1.0f / B) - m * m;
    float s2_ = gamma[c] * rsqrtf(v + 1e-5f);
    sc[c] = s2_; sh[c] = beta[c] - m * s2_;
  }
  __syncthreads();
  for (int i = tid; i < 32 * 128; i += 512) {   // 32 rows x 128 vec4
    int r = i >> 7, k4 = (i & 127) * 4;
    ushort4 gv = *(const ushort4*)&ga[(size_t)(rbase + r) * H + k4];
    ushort4 o;
    o.x = f2bf(fmaf(bf2f(gv.x), sc[k4 + 0], sh[k4 + 0]));
    o.y = f2bf(fmaf(bf2f(gv.y), sc[k4 + 1], sh[k4 + 1]));
    o.z = f2bf(fmaf(bf2f(gv.z), sc[k4 + 2], sh[k4 + 2]));
    o.w = f2bf(fmaf(bf2f(gv.w), sc[k4 + 3], sh[k4 + 3]));
    *(ushort4*)&at[r * 520 + k4] = o;
  }
  __syncthreads();

  const int w = tid >> 6, lane = tid & 63, lr = lane & 15, lg = lane >> 4;
  const int col = w * 16 + lr;              // 0..127 (w4t zero-padded)
  f32x4 acc[2];
  acc[0] = (f32x4)(0.0f); acc[1] = (f32x4)(0.0f);
#pragma unroll
  for (int ks = 0; ks < 16; ks++) {
    bf8 b = *(const bf8*)(w4t + col * H + ks * 32 + lg * 8);
#pragma unroll
    for (int mi = 0; mi < 2; mi++) {
      bf8 a = *(const bf8*)&at[(mi * 16 + lr) * 520 + ks * 32 + lg * 8];
      acc[mi] = mfma16(a, b, acc[mi]);
    }
  }

  uint32_t k0, k1;
  step_keys(s, k0, k1);
#pragma unroll
  for (int mi = 0; mi < 2; mi++) {
    float zz[4] = {0, 0, 0, 0}, zw[4] = {0, 0, 0, 0};
    if (col < DD) {
      float bb = b4[col];
#pragma unroll
      for (int r = 0; r < 4; r++) {
        int lrow = lb + mi * 16 + lg * 4 + r;   // row within this step's batch
        float z = acc[mi][r] + bb;
        uint32_t m = (uint32_t)lrow * (uint32_t)DD + (uint32_t)col;
        float dW = 0.125f * jax_normal_from_bits(jax_bits(k0, k1, m));
        zz[r] = z * z;
        zw[r] = z * dW;
      }
    }
#pragma unroll
    for (int r = 0; r < 4; r++) {
      zz[r] += __shfl_xor(zz[r], 1); zz[r] += __shfl_xor(zz[r], 2);
      zz[r] += __shfl_xor(zz[r], 4); zz[r] += __shfl_xor(zz[r], 8);
      zw[r] += __shfl_xor(zw[r], 1); zw[r] += __shfl_xor(zw[r], 2);
      zw[r] += __shfl_xor(zw[r], 4); zw[r] += __shfl_xor(zw[r], 8);
    }
    if (lr == 0) {
#pragma unroll
      for (int r = 0; r < 4; r++) {
        ys1[w][mi * 16 + lg * 4 + r] = zz[r];
        ys2[w][mi * 16 + lg * 4 + r] = zw[r];
      }
    }
  }
  __syncthreads();
  if (tid < 32) {
    float s1 = 0.0f, s2_ = 0.0f;
#pragma unroll
    for (int i = 0; i < 8; i++) { s1 += ys1[i][tid]; s2_ += ys2[i][tid]; }
    unsafeAtomicAdd(&y[lb + tid], 0.5f * dt * s1 + s2_);
  }
}

// ================================================================
// =============  ROUND-9 COOPERATIVE FALLBACK PATH  ==============
// ================================================================

__device__ __forceinline__ void gbar(int* cnt, int* gen, int mode)
{
  if (mode) __builtin_amdgcn_fence(__ATOMIC_RELEASE, "agent");
  __syncthreads();
  if (threadIdx.x == 0) {
    int g = aload_i(gen);
    int a = __hip_atomic_fetch_add(cnt, 1, __ATOMIC_RELAXED, __HIP_MEMORY_SCOPE_AGENT);
    if (a == NBLK - 1) {
      __hip_atomic_store(cnt, 0, __ATOMIC_RELAXED, __HIP_MEMORY_SCOPE_AGENT);
      __hip_atomic_store(gen, g + 1, __ATOMIC_RELAXED, __HIP_MEMORY_SCOPE_AGENT);
    } else {
      while (aload_i(gen) == g) __builtin_amdgcn_s_sleep(2);
    }
  }
  __syncthreads();
  if (mode) __builtin_amdgcn_fence(__ATOMIC_ACQUIRE, "agent");
  else      asm volatile("buffer_inv" ::: "memory");
}

__global__ void k_init_coop(const float* __restrict__ y0, const float* __restrict__ x0,
                            float* __restrict__ x, float* __restrict__ y,
                            float* __restrict__ bn, int* __restrict__ bar)
{
  int gid = blockIdx.x * blockDim.x + threadIdx.x;
  int stride = gridDim.x * blockDim.x;
  for (int i = gid; i < B * DX; i += stride) x[i] = x0[i % DX];
  for (int i = gid; i < B; i += stride) y[i] = y0[0];
  for (int i = gid; i < NSTEPS * 4 * H; i += stride) bn[i] = 0.0f;
  if (gid < 32) bar[gid] = 0;
}

__device__ __forceinline__ void l1_sec(const ushort* xt, const ushort* __restrict__ w1t,
                                       const float* __restrict__ b1,
                                       ushort* __restrict__ h1g,
                                       int base, int w, int lr, int lg)
{
  f32x4 a1[4];
#pragma unroll
  for (int t = 0; t < 4; t++) a1[t] = (f32x4)(0.0f);
#pragma unroll
  for (int ks = 0; ks < 4; ks++) {
    bf8 a = *(const bf8*)&xt[lr * 136 + ks * 32 + lg * 8];
#pragma unroll
    for (int t = 0; t < 4; t++) {
      int cc = w * 64 + t * 16 + lr;
      bf8 bfr = *(const bf8*)(w1t + cc * KIN + ks * 32 + lg * 8);
      a1[t] = mfma16(a, bfr, a1[t]);
    }
  }
#pragma unroll
  for (int t = 0; t < 4; t++) {
    int cc = w * 64 + t * 16 + lr;
    float bb = b1[cc];
#pragma unroll
    for (int r = 0; r < 4; r++)
      h1g[(base + lg * 4 + r) * H + cc] = f2bf(gelu(a1[t][r] + bb));
  }
}

__global__ void __launch_bounds__(NTHR, 2) k_steps(
    const ushort* __restrict__ w1t, const float* __restrict__ b1,
    const ushort* __restrict__ w2t, const float* __restrict__ b2,
    const ushort* __restrict__ w3t, const float* __restrict__ b3,
    const ushort* __restrict__ w4t, const float* __restrict__ b4,
    const float* __restrict__ ga1, const float* __restrict__ be1,
    const float* __restrict__ ga2, const float* __restrict__ be2,
    ushort* __restrict__ g1, ushort* __restrict__ g2h,
    float* __restrict__ bn, float* __restrict__ x, float* __restrict__ y,
    int* __restrict__ bar)
{
  __shared__ ushort smem[64 * 264];
  __shared__ float sc[H], sh[H];
  __shared__ float ys1[8][16], ys2[8][16];
  __shared__ int dsh[2];

  const int tid = threadIdx.x;
  const int w = tid >> 6, lane = tid & 63, lr = lane & 15, lg = lane >> 4;
  const float dt = 1.0f / NSTEPS;
  int* cnt = bar; int* gen = bar + 1;
  int* bins = bar + 2;
  int* gcnt = bar + 18;

  int sgs, mode;
  {
    if (tid == 0) {
      uint32_t xcc = __builtin_amdgcn_s_getreg(20 | (31 << 11)) & 15u;
      int j = __hip_atomic_fetch_add(&bins[xcc], 1, __ATOMIC_RELAXED, __HIP_MEMORY_SCOPE_AGENT);
      dsh[0] = (int)xcc; dsh[1] = j;
    }
    gbar(cnt, gen, 1);
    if (tid == 0) {
      int ok = 1;
      for (int k = 0; k < 8; k++)  ok &= (aload_i(&bins[k]) == 32);
      for (int k = 8; k < 16; k++) ok &= (aload_i(&bins[k]) == 0);
      if (ok) { dsh[0] = dsh[0] * 32 + dsh[1]; dsh[1] = 0; }
      else {
        dsh[0] = __hip_atomic_fetch_add(gcnt, 1, __ATOMIC_RELAXED, __HIP_MEMORY_SCOPE_AGENT);
        dsh[1] = 1;
      }
    }
    __syncthreads();
    sgs = dsh[0]; mode = dsh[1];
  }
  const int mb = sgs >> 2, q = sgs & 3;
  const int cbase = sgs * 16;

  {
    ushort* xt = smem;
    for (int i = tid; i < 16 * KIN; i += NTHR) {
      int r = i >> 7, k = i & (KIN - 1);
      xt[r * 136 + k] = (k < DX) ? f2bf(x[(cbase + r) * DX + k]) : (ushort)0;
    }
    __syncthreads();
    l1_sec(xt, w1t, b1, g2h, cbase, w, lr, lg);
  }
  gbar(cnt, gen, mode);

  for (int s = 0; s < NSTEPS; ++s) {
    float* bn1s = bn + s * 4 * H;
    float* bn1q = bn1s + H;
    float* bn2s = bn1s + 2 * H;
    float* bn2q = bn1s + 3 * H;

    {
      const int col = q * 128 + w * 16 + lr;
      f32x4 acc[4];
#pragma unroll
      for (int mi = 0; mi < 4; mi++) acc[mi] = (f32x4)(0.0f);
#pragma unroll
      for (int c = 0; c < 2; c++) {
        if (c) __syncthreads();
        for (int i = tid; i < 2048; i += NTHR) {
          int r = i >> 5, kk = (i & 31) * 8;
          *(bf8*)&smem[r * 264 + kk] = *(const bf8*)&g2h[(mb * 64 + r) * H + c * 256 + kk];
        }
        __syncthreads();
#pragma unroll
        for (int ks = 0; ks < 8; ks++) {
          bf8 b = *(const bf8*)(w2t + col * H + c * 256 + ks * 32 + lg * 8);
#pragma unroll
          for (int mi = 0; mi < 4; mi++) {
            bf8 a = *(const bf8*)&smem[(mi * 16 + lr) * 264 + ks * 32 + lg * 8];
            acc[mi] = mfma16(a, b, acc[mi]);
          }
        }
      }
      float bb = b2[col], ssum = 0.0f, qsum = 0.0f;
#pragma unroll
      for (int mi = 0; mi < 4; mi++)
#pragma unroll
        for (int r = 0; r < 4; r++) {
          float v = gelu(acc[mi][r] + bb);
          g1[(mb * 64 + mi * 16 + lg * 4 + r) * H + col] = f2bf(v);
          ssum += v; qsum += v * v;
        }
      ssum += __shfl_xor(ssum, 16); ssum += __shfl_xor(ssum, 32);
      qsum += __shfl_xor(qsum, 16); qsum += __shfl_xor(qsum, 32);
      if (lane < 16) { unsafeAtomicAdd(&bn1s[col], ssum); unsafeAtomicAdd(&bn1q[col], qsum); }
    }
    gbar(cnt, gen, mode);

    {
      const int col = q * 128 + w * 16 + lr;
      for (int c = tid; c < H; c += NTHR) {
        float m = aload_f(&bn1s[c]) * (1.0f / B);
        float v = aload_f(&bn1q[c]) * (1.0f / B) - m * m;
        float s2_ = ga1[c] * rsqrtf(v + 1e-5f);
        sc[c] = s2_; sh[c] = be1[c] - m * s2_;
      }
      __syncthreads();
      f32x4 acc[4];
#pragma unroll
      for (int mi = 0; mi < 4; mi++) acc[mi] = (f32x4)(0.0f);
#pragma unroll
      for (int c = 0; c < 2; c++) {
        if (c) __syncthreads();
        for (int i = tid; i < 4096; i += NTHR) {
          int r = i >> 6, k4 = (i & 63) * 4, gk = c * 256 + k4;
          ushort4 gv = *(const ushort4*)&g1[(mb * 64 + r) * H + gk];
          ushort4 o;
          o.x = f2bf(fmaf(bf2f(gv.x), sc[gk + 0], sh[gk + 0]));
          o.y = f2bf(fmaf(bf2f(gv.y), sc[gk + 1], sh[gk + 1]));
          o.z = f2bf(fmaf(bf2f(gv.z), sc[gk + 2], sh[gk + 2]));
          o.w = f2bf(fmaf(bf2f(gv.w), sc[gk + 3], sh[gk + 3]));
          *(ushort4*)&smem[r * 264 + k4] = o;
        }
        __syncthreads();
#pragma unroll
        for (int ks = 0; ks < 8; ks++) {
          bf8 b = *(const bf8*)(w3t + col * H + c * 256 + ks * 32 + lg * 8);
#pragma unroll
          for (int mi = 0; mi < 4; mi++) {
            bf8 a = *(const bf8*)&smem[(mi * 16 + lr) * 264 + ks * 32 + lg * 8];
            acc[mi] = mfma16(a, b, acc[mi]);
          }
        }
      }
      float bb = b3[col], ssum = 0.0f, qsum = 0.0f;
#pragma unroll
      for (int mi = 0; mi < 4; mi++)
#pragma unroll
        for (int r = 0; r < 4; r++) {
          float v = gelu(acc[mi][r] + bb);
          g2h[(mb * 64 + mi * 16 + lg * 4 + r) * H + col] = f2bf(v);
          ssum += v; qsum += v * v;
        }
      ssum += __shfl_xor(ssum, 16); ssum += __shfl_xor(ssum, 32);
      qsum += __shfl_xor(qsum, 16); qsum += __shfl_xor(qsum, 32);
      if (lane < 16) { unsafeAtomicAdd(&bn2s[col], ssum); unsafeAtomicAdd(&bn2q[col], qsum); }
    }
    gbar(cnt, gen, mode);

    {
      ushort* at16 = smem;
      ushort* xt   = smem + 16 * 520;
      for (int c = tid; c < H; c += NTHR) {
        float m = aload_f(&bn2s[c]) * (1.0f / B);
        float v = aload_f(&bn2q[c]) * (1.0f / B) - m * m;
        float s2_ = ga2[c] * rsqrtf(v + 1e-5f);
        sc[c] = s2_; sh[c] = be2[c] - m * s2_;
      }
      __syncthreads();
      for (int i = tid; i < 2048; i += NTHR) {
        int r = i >> 7, k4 = (i & 127) * 4;
        ushort4 gv = *(const ushort4*)&g2h[(cbase + r) * H + k4];
        ushort4 o;
        o.x = f2bf(fmaf(bf2f(gv.x), sc[k4 + 0], sh[k4 + 0]));
        o.y = f2bf(fmaf(bf2f(gv.y), sc[k4 + 1], sh[k4 + 1]));
        o.z = f2bf(fmaf(bf2f(gv.z), sc[k4 + 2], sh[k4 + 2]));
        o.w = f2bf(fmaf(bf2f(gv.w), sc[k4 + 3], sh[k4 + 3]));
        *(ushort4*)&at16[r * 520 + k4] = o;
      }
      __syncthreads();

      const int col = w * 16 + lr;
      f32x4 acc = (f32x4)(0.0f);
#pragma unroll
      for (int ks = 0; ks < 16; ks++) {
        bf8 a = *(const bf8*)&at16[lr * 520 + ks * 32 + lg * 8];
        bf8 b = *(const bf8*)(w4t + col * H + ks * 32 + lg * 8);
        acc = mfma16(a, b, acc);
      }

      uint32_t k0, k1;
      step_keys(s, k0, k1);
      float zz[4] = {0, 0, 0, 0}, zw[4] = {0, 0, 0, 0};
      float tnext = (float)(s + 1) * dt;
      if (col < DD) {
        float bb = b4[col];
#pragma unroll
        for (int r = 0; r < 4; r++) {
          int row = lg * 4 + r, grow = cbase + row;
          float z = acc[r] + bb;
          uint32_t m = (uint32_t)grow * (uint32_t)DD + (uint32_t)col;
          float dW = 0.125f * jax_normal_from_bits(jax_bits(k0, k1, m));
          float xn = x[grow * DX + col] + 1.4142135623730951f * dW;
          x[grow * DX + col] = xn;
          xt[row * 136 + col] = f2bf(xn);
          zz[r] = z * z;
          zw[r] = z * dW;
        }
      } else {
#pragma unroll
        for (int r = 0; r < 4; r++)
          xt[(lg * 4 + r) * 136 + col] = (col == DX) ? f2bf(tnext) : (ushort)0;
      }
#pragma unroll
      for (int r = 0; r < 4; r++) {
        zz[r] += __shfl_xor(zz[r], 1); zz[r] += __shfl_xor(zz[r], 2);
        zz[r] += __shfl_xor(zz[r], 4); zz[r] += __shfl_xor(zz[r], 8);
        zw[r] += __shfl_xor(zw[r], 1); zw[r] += __shfl_xor(zw[r], 2);
        zw[r] += __shfl_xor(zw[r], 4); zw[r] += __shfl_xor(zw[r], 8);
      }
      if (lr == 0) {
#pragma unroll
        for (int r = 0; r < 4; r++) {
          ys1[w][lg * 4 + r] = zz[r];
          ys2[w][lg * 4 + r] = zw[r];
        }
      }
      __syncthreads();
      if (tid < 16) {
        float s1 = 0.0f, s2_ = 0.0f;
#pragma unroll
        for (int i = 0; i < 8; i++) { s1 += ys1[i][tid]; s2_ += ys2[i][tid]; }
        y[cbase + tid] += 0.5f * dt * s1 + s2_;
      }
      if (s < NSTEPS - 1)
        l1_sec(xt, w1t, b1, g2h, cbase, w, lr, lg);
    }
    if (s < NSTEPS - 1) gbar(cnt, gen, mode);
  }
}

// ================================================================

extern "C" void kernel_launch(void* const* d_in, const int* in_sizes, int n_in,
                              void* d_out, int out_size, void* d_ws, size_t ws_size,
                              hipStream_t stream)
{
  const float* y0  = (const float*)d_in[0];
  const float* W1  = (const float*)d_in[1];
  const float* b1  = (const float*)d_in[2];
  const float* W2  = (const float*)d_in[3];
  const float* b2  = (const float*)d_in[4];
  const float* W3  = (const float*)d_in[5];
  const float* b3  = (const float*)d_in[6];
  const float* W4  = (const float*)d_in[7];
  const float* b4  = (const float*)d_in[8];
  const float* ga1 = (const float*)d_in[9];
  const float* be1 = (const float*)d_in[10];
  const float* ga2 = (const float*)d_in[11];
  const float* be2 = (const float*)d_in[12];
  const float* x0  = (const float*)d_in[13];

  float* x = (float*)d_out;        // B*DX
  float* y = x + B * DX;           // B

  // chunked path sizing: fixed = bn + x_run + weights; per-step = ga + gb
  const size_t fixed_b = (size_t)NSTEPS * 4 * H * 4 + (size_t)B * DX * 4 +
                         (size_t)(H * KIN + H * H + H * H + N4 * H) * 2;
  const size_t per_b = (size_t)B * H * 2 * 2;    // ga + gb per step
  long smax = ((long)ws_size - (long)fixed_b) / (long)per_b;
  int S = (int)(smax < 64 ? smax : 64);

  if (S >= 1) {
    // ---------------- chunked step-parallel path ----------------
    float* bn    = (float*)d_ws;                       // NSTEPS*4*H
    float* x_run = bn + NSTEPS * 4 * H;                // B*DX
    ushort* w1t = (ushort*)(x_run + B * DX);
    ushort* w2t = w1t + H * KIN;
    ushort* w3t = w2t + H * H;
    ushort* w4t = w3t + H * H;
    ushort* ga  = w4t + N4 * H;                        // S*B*H (xs at its front)
    ushort* gb  = ga + (size_t)S * B * H;              // S*B*H
    ushort* xs  = ga;   // xs consumed by kL12 before kL3 overwrites ga

    k_init_chunk<<<256, 256, 0, stream>>>(y0, x0, x_run, y, bn);
    k_prep<<<512, 256, 0, stream>>>(W1, W2, W3, W4, w1t, w2t, w3t, w4t);

    for (int s0 = 0; s0 < NSTEPS; s0 += S) {
      int Sc = (NSTEPS - s0 < S) ? (NSTEPS - s0) : S;
      k_xs<<<(B * KIN) / 256, 256, 0, stream>>>(x_run, xs, x, s0, Sc);
      kL12<<<Sc * 128, 256, 0, stream>>>(xs, w1t, b1, w2t, b2, gb, bn, s0);
      kL3 <<<Sc * 128, 256, 0, stream>>>(gb, bn, s0, ga1, be1, w3t, b3, ga);
      kL4 <<<Sc * 128, 512, 0, stream>>>(ga, bn, s0, ga2, be2, w4t, b4, y);
    }
  } else {
    // ---------------- round-9 cooperative fallback ----------------
    int*   bar = (int*)d_ws;
    float* bn  = (float*)d_ws + 32;
    ushort* ub  = (ushort*)(bn + NSTEPS * 4 * H);
    ushort* g1  = ub;
    ushort* g2h = g1 + B * H;
    ushort* w1t = g2h + B * H;
    ushort* w2t = w1t + H * KIN;
    ushort* w3t = w2t + H * H;
    ushort* w4t = w3t + H * H;

    k_init_coop<<<256, 256, 0, stream>>>(y0, x0, x, y, bn, bar);
    k_prep<<<512, 256, 0, stream>>>(W1, W2, W3, W4, w1t, w2t, w3t, w4t);

    void* args[] = {
      (void*)&w1t, (void*)&b1, (void*)&w2t, (void*)&b2,
      (void*)&w3t, (void*)&b3, (void*)&w4t, (void*)&b4,
      (void*)&ga1, (void*)&be1, (void*)&ga2, (void*)&be2,
      (void*)&g1, (void*)&g2h, (void*)&bn, (void*)&x, (void*)&y, (void*)&bar
    };
    hipLaunchCooperativeKernel((const void*)k_steps, dim3(NBLK), dim3(NTHR),
                               args, 0, stream);
  }
}